// Round 7
// baseline (1265.623 us; speedup 1.0000x reference)
//
#include <hip/hip_runtime.h>

typedef unsigned short u16;
typedef unsigned int u32;

#define W_ 224
#define H_ 128
#define C_ 128
#define NH 8
#define HD 16
#define ROWS_ (W_ * H_)          // 28672 rows per image
#define PREP_STRIDE 4128
#define KSTR 40
#define VSTR 232
#define TROWS 32                 // rows per tab_kernel block

typedef __bf16 bf16x8 __attribute__((ext_vector_type(8)));
typedef float f32x4 __attribute__((ext_vector_type(4)));

__device__ __forceinline__ u16 f2bf(float f) {
  u32 u = __float_as_uint(f);
  return (u16)((u + 0x7FFFu + ((u >> 16) & 1u)) >> 16);
}
// Packed RNE f32->bf16 pair: single v_cvt_pk_bf16_f32 (same rounding as f2bf).
__device__ __forceinline__ u32 cvtpk(float lo, float hi) {
  u32 r;
  asm("v_cvt_pk_bf16_f32 %0, %1, %2" : "=v"(r) : "v"(lo), "v"(hi));
  return r;
}
__device__ __forceinline__ float bflo(u32 u) { return __uint_as_float(u << 16); }
__device__ __forceinline__ float bfhi(u32 u) { return __uint_as_float(u & 0xFFFF0000u); }

#if __has_builtin(__builtin_amdgcn_exp2f)
#define EX2(x) __builtin_amdgcn_exp2f(x)
#else
#define EX2(x) __expf((x) * 0.6931471805599453f)
#endif

// ---------------------------------------------------------------------------
// Rank-1 PE decomposition prep: grid (12 s, 8 e-groups), LDS-staged, coalesced.
// ---------------------------------------------------------------------------
__global__ __launch_bounds__(256) void prep_kernel(
    const float* __restrict__ self_Wi, const float* __restrict__ self_bi,
    const float* __restrict__ cross_Wi, const float* __restrict__ cross_bi,
    float* __restrict__ prep) {
  __shared__ float Wq[16][132];
  __shared__ float Wk[16][132];
  __shared__ float u[128];
  __shared__ float Aq[16], Ak[16], bq[16], bk[16];
  const int s = blockIdx.x, e = blockIdx.y, l = s >> 1;
  const float* Wi = (s & 1) ? cross_Wi + (size_t)l * 384 * 128 : self_Wi + (size_t)l * 384 * 128;
  const float* bi = (s & 1) ? cross_bi + l * 384 : self_bi + l * 384;
  const int tid = threadIdx.x;
  if (tid < 128) {
    float ex = (float)(tid & ~1) * (1.f / 128.f);
    u[tid] = expf(-ex * logf(10000.f));
  }
  if (tid >= 128 && tid < 144) { int r = tid - 128; bq[r] = bi[e * 16 + r]; }
  if (tid >= 160 && tid < 176) { int r = tid - 160; bk[r] = bi[128 + e * 16 + r]; }
  for (int t = tid; t < 2048; t += 256) {
    int r = t >> 7, f = t & 127;
    Wq[r][f] = Wi[(size_t)(e * 16 + r) * 128 + f];
    Wk[r][f] = Wi[(size_t)(128 + e * 16 + r) * 128 + f];
  }
  __syncthreads();
  {
    const int grp = tid >> 3;
    const int lg = tid & 7;
    const float* row = (grp < 16) ? Wq[grp] : Wk[grp - 16];
    float a = 0.f;
#pragma unroll
    for (int i = 0; i < 16; ++i) a += row[lg * 16 + i] * u[lg * 16 + i];
    a += __shfl_xor(a, 1);
    a += __shfl_xor(a, 2);
    a += __shfl_xor(a, 4);
    if (lg == 0) {
      if (grp < 16) Aq[grp] = a;
      else          Ak[grp - 16] = a;
    }
  }
  __syncthreads();
  float* out = prep + (size_t)s * PREP_STRIDE;
  for (int t = tid; t < 512; t += 256) {
    int v = t >> 7, f = t & 127;
    float acc = 0.f;
#pragma unroll
    for (int c = 0; c < 16; ++c) {
      if (v == 0)      acc += Wq[c][f] * Ak[c];
      else if (v == 1) acc += Wq[c][f] * bk[c];
      else if (v == 2) acc += Wk[c][f] * Aq[c];
      else             acc += Wk[c][f] * bq[c];
    }
    out[v * 1024 + e * 128 + f] = acc * 0.25f;
  }
  if (tid < 4) {
    int v = tid;
    float acc = 0.f;
#pragma unroll
    for (int c = 0; c < 16; ++c) {
      if (v == 0)      acc += bq[c] * Ak[c];
      else if (v == 1) acc += bq[c] * bk[c];
      else if (v == 2) acc += bk[c] * Aq[c];
      else             acc += bk[c] * bq[c];
    }
    out[4096 + v * 8 + e] = acc * 0.25f;
  }
}

// ---------------------------------------------------------------------------
// Fused LN + affine-PE tables, 32 rows per block. X = LN(X) in place + bf16
// copy XB + fp32 alpha/beta/gamma/delta tables. Scalar phase 2 (stride-133
// ws, 0 bank conflicts) — R3-verified; the MFMA variant tripped the graph
// tripwire in R4 and stays out until root-caused.
// R7: LN phase batches all 8 row loads up front (8 global loads in flight,
// then 8 independent shuffle-reduce chains interleave on the VALU) instead of
// serial load->12-deep-chain->load per row. Per-row math and write addresses
// unchanged -> XA/XB/tables bit-identical; pure latency/ILP fix for the
// 41us, VALU 37%/HBM 22%/nothing-saturated profile.
// ---------------------------------------------------------------------------
__global__ __launch_bounds__(256) void tab_kernel(
    float* __restrict__ x, const float* __restrict__ g,
    const float* __restrict__ b, const float* __restrict__ wq,
    const float* __restrict__ cq, float* __restrict__ outA, float* __restrict__ outB,
    const float* __restrict__ wk, const float* __restrict__ ck,
    float* __restrict__ outG, float* __restrict__ outD,
    u16* __restrict__ xb, int mode) {
  __shared__ float ys[TROWS][132];
  __shared__ float ws[32][133];
  const int tid = threadIdx.x;
  for (int t = tid; t < 2048; t += 256) ws[t >> 7][t & 127] = wq[t];
  for (int t = tid; t < 2048; t += 256) ws[16 + (t >> 7)][t & 127] = wk[t];
  const int wv = tid >> 6, lane = tid & 63;
  const int base = blockIdx.x * TROWS;
  {
    float2 gg = ((const float2*)g)[lane];
    float2 bb = ((const float2*)b)[lane];
    // batch the 8 row loads (independent, in flight together)
    float2 vv[8];
#pragma unroll
    for (int t = 0; t < 8; ++t) {
      const int r = wv * 8 + t;
      vv[t] = ((const float2*)(x + (size_t)(base + r) * 128))[lane];
    }
    // 8 independent reduce+write chains; compiler interleaves across VALU
#pragma unroll
    for (int t = 0; t < 8; ++t) {
      const int r = wv * 8 + t;
      float2 v = vv[t];
      float s1 = v.x + v.y, s2 = v.x * v.x + v.y * v.y;
#pragma unroll
      for (int k = 1; k < 64; k <<= 1) {
        s1 += __shfl_xor(s1, k);
        s2 += __shfl_xor(s2, k);
      }
      float mean = s1 * (1.f / 128.f);
      float var = s2 * (1.f / 128.f) - mean * mean;
      float rstd = rsqrtf(var + 1e-5f);
      float y0 = (v.x - mean) * rstd * gg.x + bb.x;
      float y1 = (v.y - mean) * rstd * gg.y + bb.y;
      ((float2*)(x + (size_t)(base + r) * 128))[lane] = make_float2(y0, y1);
      ((u32*)xb)[(size_t)(base + r) * 64 + lane] = cvtpk(y0, y1);
      ys[r][2 * lane] = y0;
      ys[r][2 * lane + 1] = y1;
    }
  }
  __syncthreads();
  const int c = tid & 31;
  const int rg = (tid >> 5) * 4;
  const int side = c >> 4, oo = c & 15;
  const float* wrow = ws[c];
  const int val = oo >> 3, e = oo & 7;
  const float cadd = side ? ck[val * 8 + e] : cq[val * 8 + e];
  float* dst = side ? (val ? outD : outG) : (val ? outB : outA);
#pragma unroll
  for (int rr = 0; rr < 4; ++rr) {
    const int p = base + rg + rr;
    const int half = (p >= ROWS_) ? 1 : 0;
    const int ploc = p - half * ROWS_;
    const bool active = (mode == 0) || (half ? (side == 0) : (side == 1));
    if (active) {
      const float* yr = ys[rg + rr];
      float a0 = 0.f, a1 = 0.f, a2 = 0.f, a3 = 0.f;
#pragma unroll 4
      for (int f = 0; f < 128; f += 4) {
        a0 += yr[f] * wrow[f];
        a1 += yr[f + 1] * wrow[f + 1];
        a2 += yr[f + 2] * wrow[f + 2];
        a3 += yr[f + 3] * wrow[f + 3];
      }
      float acc = (a0 + a1) + (a2 + a3);
      int i = ploc >> 7, blow = ploc & 127;
      int b_out = (mode == 0) ? half * 128 + blow : blow;
      dst[((size_t)(b_out * 8 + e)) * 224 + i] = acc + cadd;
    }
  }
}

// ---------------------------------------------------------------------------
// Plain 64x64-tile bf16 MFMA GEMM (bf16 A input) — R3-verified version.
// R5's 64x128 rewrite regressed +53us (52KB LDS -> 3 blocks/CU, halved wave
// count; saved bytes were L2-hits, not HBM). Reverted.
// mode 4: fout += acc + bias (out-proj residual); mode 5: fout = acc + bias.
// ---------------------------------------------------------------------------
__global__ __launch_bounds__(256) void gemm_plain(
    const u16* __restrict__ A, const u16* __restrict__ B,
    const float* __restrict__ bias, int mode, float* __restrict__ fout) {
  __shared__ u16 As[64 * 136];
  __shared__ u16 Bs[64 * 136];
  const int tid = threadIdx.x;
  const int M0 = blockIdx.x * 64, N0 = blockIdx.y * 64;
  const uint4* Ag = (const uint4*)(A + (size_t)M0 * 128);
  const uint4* Bg = (const uint4*)(B + (size_t)N0 * 128);
  for (int t = tid; t < 1024; t += 256) {
    int row = t >> 4, cc = t & 15;
    *(uint4*)&As[row * 136 + cc * 8] = Ag[row * 16 + cc];
  }
  for (int t = tid; t < 1024; t += 256) {
    int row = t >> 4, cc = t & 15;
    *(uint4*)&Bs[row * 136 + cc * 8] = Bg[row * 16 + cc];
  }
  __syncthreads();
  const int wave = tid >> 6, lane = tid & 63;
  const int wm = (wave >> 1) * 32, wn = (wave & 1) * 32;
  const int lr = lane & 15, kq = (lane >> 4) * 8;
  f32x4 acc[2][2] = {};
#pragma unroll
  for (int ks = 0; ks < 4; ++ks) {
    int ko = ks * 32 + kq;
    bf16x8 a0 = *(const bf16x8*)&As[(wm + lr) * 136 + ko];
    bf16x8 a1 = *(const bf16x8*)&As[(wm + 16 + lr) * 136 + ko];
    bf16x8 b0 = *(const bf16x8*)&Bs[(wn + lr) * 136 + ko];
    bf16x8 b1 = *(const bf16x8*)&Bs[(wn + 16 + lr) * 136 + ko];
    acc[0][0] = __builtin_amdgcn_mfma_f32_16x16x32_bf16(a0, b0, acc[0][0], 0, 0, 0);
    acc[0][1] = __builtin_amdgcn_mfma_f32_16x16x32_bf16(a0, b1, acc[0][1], 0, 0, 0);
    acc[1][0] = __builtin_amdgcn_mfma_f32_16x16x32_bf16(a1, b0, acc[1][0], 0, 0, 0);
    acc[1][1] = __builtin_amdgcn_mfma_f32_16x16x32_bf16(a1, b1, acc[1][1], 0, 0, 0);
  }
  const int colq = lane & 15, rowq = (lane >> 4) * 4;
#pragma unroll
  for (int tm = 0; tm < 2; ++tm)
#pragma unroll
    for (int tn = 0; tn < 2; ++tn) {
#pragma unroll
      for (int r = 0; r < 4; ++r) {
        int row = M0 + wm + tm * 16 + rowq + r;
        int col = N0 + wn + tn * 16 + colq;
        float v = acc[tm][tn][r] + bias[col];
        if (mode == 4) fout[(size_t)row * 128 + col] += v;
        else           fout[(size_t)row * 128 + col] = v;
      }
    }
}

// ---------------------------------------------------------------------------
// Self QKV GEMM: 128x128 tiles, 512 threads (8 waves, each 64x32). A from XB.
// ---------------------------------------------------------------------------
__global__ __launch_bounds__(512) void gemm_qkv_self(
    const u16* __restrict__ X, const u16* __restrict__ Bw,
    const float* __restrict__ bias, u16* __restrict__ o0, u16* __restrict__ o1,
    u16* __restrict__ o2) {
  __shared__ u16 As[128 * 136];
  __shared__ u16 Bs[128 * 136];
  const int tid = threadIdx.x;
  const int M0 = blockIdx.x * 128, N0 = blockIdx.y * 128;
  {
    const uint4* Bg = (const uint4*)(Bw + (size_t)N0 * 128);
    const uint4* Ag = (const uint4*)(X + (size_t)M0 * 128);
    for (int t = tid; t < 2048; t += 512) {
      int row = t >> 4, cc = t & 15;
      *(uint4*)&As[row * 136 + cc * 8] = Ag[row * 16 + cc];
      *(uint4*)&Bs[row * 136 + cc * 8] = Bg[row * 16 + cc];
    }
  }
  __syncthreads();
  const int wave = tid >> 6, lane = tid & 63;
  const int wm = (wave >> 2) * 64, wn = (wave & 3) * 32;
  const int lr = lane & 15, kq = (lane >> 4) * 8;
  f32x4 acc[4][2] = {};
#pragma unroll
  for (int ks = 0; ks < 4; ++ks) {
    int ko = ks * 32 + kq;
    bf16x8 b0 = *(const bf16x8*)&Bs[(wn + lr) * 136 + ko];
    bf16x8 b1 = *(const bf16x8*)&Bs[(wn + 16 + lr) * 136 + ko];
#pragma unroll
    for (int tm = 0; tm < 4; ++tm) {
      bf16x8 a0 = *(const bf16x8*)&As[(wm + tm * 16 + lr) * 136 + ko];
      acc[tm][0] = __builtin_amdgcn_mfma_f32_16x16x32_bf16(a0, b0, acc[tm][0], 0, 0, 0);
      acc[tm][1] = __builtin_amdgcn_mfma_f32_16x16x32_bf16(a0, b1, acc[tm][1], 0, 0, 0);
    }
  }
  const int colq = lane & 15, rowq = (lane >> 4) * 4;
#pragma unroll
  for (int tm = 0; tm < 4; ++tm)
#pragma unroll
    for (int tn = 0; tn < 2; ++tn) {
#pragma unroll
      for (int r = 0; r < 4; ++r) {
        int row = M0 + wm + tm * 16 + rowq + r;
        int col = N0 + wn + tn * 16 + colq;
        float v = acc[tm][tn][r] + bias[col];
        int part = col >> 7;
        int cc = col & 127;
        int e = cc >> 4, c = cc & 15;
        int rloc = row, badd = 0;
        if (row >= ROWS_) { rloc = row - ROWS_; badd = 128; }
        int b = (rloc & 127) + badd, pos = rloc >> 7;
        size_t off = ((size_t)(b * NH + e) * W_ + pos) * HD + c;
        if (part == 0)      o0[off] = f2bf(v * 0.25f);
        else if (part == 1) o1[off] = f2bf(v);
        else                o2[off] = f2bf(v);
      }
    }
}

// ---------------------------------------------------------------------------
// Cross QKV GEMM: 128x128 tiles, 512 threads.
// y=0: q from Xr (*0.25); y=1: K from Xl; y=2: V from Xl.
// At l=5 launched with grid.y=2 (V dead: no attn launch, corresp reads Q/K).
// ---------------------------------------------------------------------------
__global__ __launch_bounds__(512) void gemm_qkv_cross(
    const u16* __restrict__ Xl, const u16* __restrict__ Xr,
    const u16* __restrict__ cWi, const float* __restrict__ cbi,
    u16* __restrict__ QB, u16* __restrict__ KB, u16* __restrict__ VB) {
  __shared__ u16 As[128 * 136];
  __shared__ u16 Bs[128 * 136];
  const int tid = threadIdx.x;
  const int M0 = blockIdx.x * 128;
  const int y = blockIdx.y;
  const u16* X = (y == 0) ? Xr : Xl;
  const u16* Bw = cWi + (size_t)y * 128 * 128;
  const float* bias = cbi + y * 128;
  {
    const uint4* Bg = (const uint4*)Bw;
    const uint4* Ag = (const uint4*)(X + (size_t)M0 * 128);
    for (int t = tid; t < 2048; t += 512) {
      int row = t >> 4, cc = t & 15;
      *(uint4*)&As[row * 136 + cc * 8] = Ag[row * 16 + cc];
      *(uint4*)&Bs[row * 136 + cc * 8] = Bg[row * 16 + cc];
    }
  }
  __syncthreads();
  const int wave = tid >> 6, lane = tid & 63;
  const int wm = (wave >> 2) * 64, wn = (wave & 3) * 32;
  const int lr = lane & 15, kq = (lane >> 4) * 8;
  f32x4 acc[4][2] = {};
#pragma unroll
  for (int ks = 0; ks < 4; ++ks) {
    int ko = ks * 32 + kq;
    bf16x8 b0 = *(const bf16x8*)&Bs[(wn + lr) * 136 + ko];
    bf16x8 b1 = *(const bf16x8*)&Bs[(wn + 16 + lr) * 136 + ko];
#pragma unroll
    for (int tm = 0; tm < 4; ++tm) {
      bf16x8 a0 = *(const bf16x8*)&As[(wm + tm * 16 + lr) * 136 + ko];
      acc[tm][0] = __builtin_amdgcn_mfma_f32_16x16x32_bf16(a0, b0, acc[tm][0], 0, 0, 0);
      acc[tm][1] = __builtin_amdgcn_mfma_f32_16x16x32_bf16(a0, b1, acc[tm][1], 0, 0, 0);
    }
  }
  u16* outp = (y == 0) ? QB : ((y == 1) ? KB : VB);
  const float scale = (y == 0) ? 0.25f : 1.f;
  const int colq = lane & 15, rowq = (lane >> 4) * 4;
#pragma unroll
  for (int tm = 0; tm < 4; ++tm)
#pragma unroll
    for (int tn = 0; tn < 2; ++tn) {
#pragma unroll
      for (int r = 0; r < 4; ++r) {
        int row = M0 + wm + tm * 16 + rowq + r;
        int col = wn + tn * 16 + colq;
        float v = (acc[tm][tn][r] + bias[col]) * scale;
        int e = col >> 4, c = col & 15;
        int b = row & 127, pos = row >> 7;
        outp[((size_t)(b * NH + e) * W_ + pos) * HD + c] = f2bf(v);
      }
    }
}

// ---------------------------------------------------------------------------
// MFMA flash attention per (head e, batch-row b). Two-pass softmax. P stays
// in registers (sigma-permuted V); exp2 with log2e folded into Q-side staging.
// ---------------------------------------------------------------------------
__global__ __launch_bounds__(448) void attn_kernel(
    const u16* __restrict__ qb, const u16* __restrict__ kb,
    const u16* __restrict__ vb, const float* __restrict__ ALPHA,
    const float* __restrict__ BETA, const float* __restrict__ GAMMA,
    const float* __restrict__ DELTA, u16* __restrict__ obuf) {
  __shared__ u16 Ksh[224 * KSTR];
  __shared__ u16 Qsh[224 * KSTR];
  __shared__ u16 Vt[16 * VSTR];
  const int e = blockIdx.x, b = blockIdx.y;
  const size_t hb = (size_t)(b * NH + e);
  const int tid = threadIdx.x;
  const u32 ONE = 0x3F80u;
  const float LOG2E = 1.4426950408889634f;

  if (tid < 224) {
    const int j = tid;
    const uint4* src = (const uint4*)(kb + (hb * W_ + j) * HD);
    uint4 a = src[0], b2 = src[1];
    *(uint4*)&Ksh[j * KSTR] = a;
    *(uint4*)&Ksh[j * KSTR + 8] = b2;
    float G = GAMMA[hb * 224 + j];
    float D = DELTA[hb * 224 + j];
    float jf = (float)j;
    float P = (G * jf + D) * LOG2E;
    u16 Phi = f2bf(P);
    float Plo = P - __uint_as_float((u32)Phi << 16);
    u32* ex = (u32*)&Ksh[j * KSTR + 16];
    ex[0] = (u32)f2bf(G * LOG2E) | ((u32)Phi << 16);
    ex[1] = (u32)f2bf(Plo) | ((u32)f2bf(jf) << 16);
    ex[2] = ONE | (ONE << 16);
#pragma unroll
    for (int z = 3; z < 12; ++z) ex[z] = 0;
    const uint4* vsrc = (const uint4*)(vb + (hb * W_ + j) * HD);
    uint4 va = vsrc[0], vb4 = vsrc[1];
    u32 w[8] = {va.x, va.y, va.z, va.w, vb4.x, vb4.y, vb4.z, vb4.w};
    // sigma-permuted column so PV A-fragments come straight from registers
    const int jl = j & 31;
    const int qcol = (j & ~31) | (((jl >> 2) & 3) << 3) | ((jl >> 4) << 2) | (jl & 3);
#pragma unroll
    for (int c = 0; c < 16; ++c)
      Vt[c * VSTR + qcol] = (c & 1) ? (u16)(w[c >> 1] >> 16) : (u16)(w[c >> 1] & 0xFFFF);
  } else {
    const int i = tid - 224;
    const uint4* src = (const uint4*)(qb + (hb * W_ + i) * HD);
    uint4 a = src[0], b2 = src[1];
    u32 qa[8] = {a.x, a.y, a.z, a.w, b2.x, b2.y, b2.z, b2.w};
#pragma unroll
    for (int t = 0; t < 8; ++t)
      qa[t] = cvtpk(bflo(qa[t]) * LOG2E, bfhi(qa[t]) * LOG2E);
    *(uint4*)&Qsh[i * KSTR] = make_uint4(qa[0], qa[1], qa[2], qa[3]);
    *(uint4*)&Qsh[i * KSTR + 8] = make_uint4(qa[4], qa[5], qa[6], qa[7]);
    float al = ALPHA[hb * 224 + i];
    float be = BETA[hb * 224 + i];
    float ifl = (float)i;
    float Q = (be - al * ifl) * LOG2E;
    u16 Qhi = f2bf(Q);
    float Qlo = Q - __uint_as_float((u32)Qhi << 16);
    u32* ex = (u32*)&Qsh[i * KSTR + 16];
    ex[0] = (u32)f2bf(-ifl) | (ONE << 16);
    ex[1] = ONE | ((u32)f2bf(al * LOG2E) << 16);
    ex[2] = (u32)Qhi | ((u32)f2bf(Qlo) << 16);
#pragma unroll
    for (int z = 3; z < 12; ++z) ex[z] = 0;
  }
  __syncthreads();

  const int wid = tid >> 6, lane = tid & 63;
  const int g = lane >> 4, li = lane & 15;
  const int obase = (b & 128) ? ROWS_ : 0;
  const int blow = b & 127;

  for (int qt = wid * 2; qt < wid * 2 + 2; ++qt) {
    const int i0 = qt * 16;
    const bf16x8 Bq = *(const bf16x8*)&Qsh[(i0 + li) * KSTR + g * 8];
    f32x4 C[7][2];
#pragma unroll
    for (int js = 0; js < 7; ++js) {
      const bf16x8 A0 = *(const bf16x8*)&Ksh[(js * 32 + li) * KSTR + g * 8];
      const bf16x8 A1 = *(const bf16x8*)&Ksh[(js * 32 + 16 + li) * KSTR + g * 8];
      const f32x4 Z = {0.f, 0.f, 0.f, 0.f};
      C[js][0] = __builtin_amdgcn_mfma_f32_16x16x32_bf16(A0, Bq, Z, 0, 0, 0);
      C[js][1] = __builtin_amdgcn_mfma_f32_16x16x32_bf16(A1, Bq, Z, 0, 0, 0);
    }
    float m = -1e30f;
#pragma unroll
    for (int js = 0; js < 7; ++js)
#pragma unroll
      for (int h = 0; h < 2; ++h)
        m = fmaxf(m, fmaxf(fmaxf(C[js][h][0], C[js][h][1]), fmaxf(C[js][h][2], C[js][h][3])));
    m = fmaxf(m, __shfl_xor(m, 16));
    m = fmaxf(m, __shfl_xor(m, 32));
    f32x4 O = {0.f, 0.f, 0.f, 0.f};
    float lsum = 0.f;
#pragma unroll
    for (int js = 0; js < 7; ++js) {
      float p0 = EX2(C[js][0][0] - m), p1 = EX2(C[js][0][1] - m);
      float p2 = EX2(C[js][0][2] - m), p3 = EX2(C[js][0][3] - m);
      float p4 = EX2(C[js][1][0] - m), p5 = EX2(C[js][1][1] - m);
      float p6 = EX2(C[js][1][2] - m), p7 = EX2(C[js][1][3] - m);
      lsum += ((p0 + p1) + (p2 + p3)) + ((p4 + p5) + (p6 + p7));
      uint4 pu = make_uint4(cvtpk(p0, p1), cvtpk(p2, p3), cvtpk(p4, p5), cvtpk(p6, p7));
      const bf16x8 Ap = __builtin_bit_cast(bf16x8, pu);
      const bf16x8 Bv = *(const bf16x8*)&Vt[li * VSTR + js * 32 + g * 8];
      O = __builtin_amdgcn_mfma_f32_16x16x32_bf16(Ap, Bv, O, 0, 0, 0);
    }
    lsum += __shfl_xor(lsum, 16);
    lsum += __shfl_xor(lsum, 32);
#pragma unroll
    for (int r = 0; r < 4; ++r) {
      const float lr = __shfl(lsum, g * 4 + r);
      const int irow = i0 + g * 4 + r;
      obuf[((size_t)(obase + irow * 128 + blow)) * C_ + e * HD + li] = f2bf(O[r] * (1.f / lr));
    }
  }
}

// Gather x_l/x_r[b][c][h][w] -> bf16 rows p = img*28672 + w*128 + h*2 + b.
__global__ __launch_bounds__(256) void transpose_kernel(const float* __restrict__ x_l,
                                                        const float* __restrict__ x_r,
                                                        u16* __restrict__ xT) {
  __shared__ float tile[128][57];
  const int wt = blockIdx.x * 56, hi = blockIdx.y;
  const int img = blockIdx.z >> 1, bi = blockIdx.z & 1;
  const float* x = img ? x_r : x_l;
  const int wave = threadIdx.x >> 6, lane = threadIdx.x & 63;
  for (int c = wave; c < 128; c += 4) {
    if (lane < 56)
      tile[c][lane] = x[(((size_t)bi * 128 + c) * 64 + hi) * 224 + wt + lane];
  }
  __syncthreads();
  u32* dst = (u32*)xT;
  for (int w = wave; w < 56; w += 4) {
    int p = img * ROWS_ + (wt + w) * 128 + hi * 2 + bi;
    float a = tile[lane * 2][w], b2 = tile[lane * 2 + 1][w];
    dst[(size_t)p * 64 + lane] = (u32)f2bf(a) | ((u32)f2bf(b2) << 16);
  }
}

// ---------------------------------------------------------------------------
// Final soft-argmax, MFMA version.
// ---------------------------------------------------------------------------
__global__ __launch_bounds__(448) void corresp_kernel(
    const u16* __restrict__ qb, const u16* __restrict__ kb,
    const float* __restrict__ ALPHA, const float* __restrict__ BETA,
    const float* __restrict__ GAMMA, const float* __restrict__ DELTA,
    float* __restrict__ out) {
  __shared__ u16 Ksh[224 * 136];   // 60,928 B
  __shared__ float Gs[224], Ds[224];
  const int b = blockIdx.x, tid = threadIdx.x;
  if (tid < 224) {
    const int j = tid;
#pragma unroll
    for (int e = 0; e < 8; ++e) {
      const uint4* src = (const uint4*)(kb + ((size_t)(b * 8 + e) * 224 + j) * 16);
      *(uint4*)&Ksh[j * 136 + e * 16] = src[0];
      *(uint4*)&Ksh[j * 136 + e * 16 + 8] = src[1];
    }
    float gs = 0.f, ds = 0.f;
#pragma unroll
    for (int e = 0; e < 8; ++e) {
      gs += GAMMA[((size_t)(b * 8 + e)) * 224 + j];
      ds += DELTA[((size_t)(b * 8 + e)) * 224 + j];
    }
    Gs[j] = gs;
    Ds[j] = ds;
  }
  __syncthreads();
  const int wid = tid >> 6, lane = tid & 63;
  const int g = lane >> 4, li = lane & 15;
  const int i = blockIdx.y * 112 + wid * 16 + li;
  bf16x8 Bq[4];
#pragma unroll
  for (int ks = 0; ks < 4; ++ks) {
    const int e2 = ks * 2 + (g >> 1), c0 = (g & 1) * 8;
    Bq[ks] = *(const bf16x8*)&qb[((size_t)(b * 8 + e2) * 224 + i) * 16 + c0];
  }
  f32x4 C[14];
#pragma unroll
  for (int js = 0; js < 14; ++js) {
    f32x4 acc = {0.f, 0.f, 0.f, 0.f};
#pragma unroll
    for (int ks = 0; ks < 4; ++ks) {
      const bf16x8 A = *(const bf16x8*)&Ksh[(js * 16 + li) * 136 + ks * 32 + g * 8];
      acc = __builtin_amdgcn_mfma_f32_16x16x32_bf16(A, Bq[ks], acc, 0, 0, 0);
    }
    C[js] = acc;
  }
  float ai = 0.f, bi_ = 0.f;
#pragma unroll
  for (int e = 0; e < 8; ++e) {
    ai += ALPHA[((size_t)(b * 8 + e)) * 224 + i];
    bi_ += BETA[((size_t)(b * 8 + e)) * 224 + i];
  }
  const float ifl = (float)i;
  float m = -1e30f;
#pragma unroll
  for (int js = 0; js < 14; ++js) {
#pragma unroll
    for (int r = 0; r < 4; ++r) {
      const int j = js * 16 + g * 4 + r;
      float s = C[js][r] + ((float)j - ifl) * (ai + Gs[j]) + bi_ + Ds[j];
      C[js][r] = s;
      m = fmaxf(m, s);
    }
  }
  m = fmaxf(m, __shfl_xor(m, 16));
  m = fmaxf(m, __shfl_xor(m, 32));
  float l = 0.f, wj = 0.f;
#pragma unroll
  for (int js = 0; js < 14; ++js) {
#pragma unroll
    for (int r = 0; r < 4; ++r) {
      const float p = __expf(C[js][r] - m);
      l += p;
      wj += p * (float)(js * 16 + g * 4 + r);
    }
  }
  l += __shfl_xor(l, 16);
  l += __shfl_xor(l, 32);
  wj += __shfl_xor(wj, 16);
  wj += __shfl_xor(wj, 32);
  if (g == 0) out[(size_t)b * 224 + i] = ifl - wj / fmaxf(l, 1e-30f);
}

// Single-launch conversion of all five weight tensors to one bf16 buffer.
#define OFF_FEAT 0
#define OFF_SWI 16384
#define OFF_SWO 311296
#define OFF_CWI 409600
#define OFF_CWO 704512
#define N_WALL 802816
__global__ __launch_bounds__(256) void cvt_all_kernel(
    const float* __restrict__ feat_w, const float* __restrict__ self_Wi,
    const float* __restrict__ self_Wo, const float* __restrict__ cross_Wi,
    const float* __restrict__ cross_Wo, u16* __restrict__ dst) {
  int idx = blockIdx.x * 256 + threadIdx.x;
  if (idx >= N_WALL) return;
  float v;
  if (idx < OFF_SWI)       v = feat_w[idx];
  else if (idx < OFF_SWO)  v = self_Wi[idx - OFF_SWI];
  else if (idx < OFF_CWI)  v = self_Wo[idx - OFF_SWO];
  else if (idx < OFF_CWO)  v = cross_Wi[idx - OFF_CWI];
  else                     v = cross_Wo[idx - OFF_CWO];
  dst[idx] = f2bf(v);
}

extern "C" void kernel_launch(void* const* d_in, const int* in_sizes, int n_in,
                              void* d_out, int out_size, void* d_ws, size_t ws_size,
                              hipStream_t stream) {
  (void)in_sizes; (void)n_in; (void)out_size; (void)ws_size;
  const float* x_l = (const float*)d_in[0];
  const float* x_r = (const float*)d_in[1];
  const float* feat_w = (const float*)d_in[2];
  const float* feat_b = (const float*)d_in[3];
  const float* self_Wi = (const float*)d_in[4];
  const float* self_bi = (const float*)d_in[5];
  const float* self_Wo = (const float*)d_in[6];
  const float* self_bo = (const float*)d_in[7];
  const float* cross_Wi = (const float*)d_in[8];
  const float* cross_bi = (const float*)d_in[9];
  const float* cross_Wo = (const float*)d_in[10];
  const float* cross_bo = (const float*)d_in[11];
  const float* ln_g = (const float*)d_in[12];
  const float* ln_b = (const float*)d_in[13];

  char* ws = (char*)d_ws;
  size_t off = 0;
  auto alloc = [&](size_t bytes) {
    char* p = ws + off;
    off += (bytes + 255) & ~(size_t)255;
    return p;
  };
  // Total ~97 MB — under the R6-proven ~112 MB budget. XB aliases OB:
  // XB live range is tab->qkv, OB live range is attn->out-proj (disjoint).
  float* XA = (float*)alloc((size_t)2 * ROWS_ * C_ * 4);   // residual (in-place LN)
  u16* QB = (u16*)alloc((size_t)256 * NH * W_ * HD * 2);   // also XT scratch
  u16* KB = (u16*)alloc((size_t)256 * NH * W_ * HD * 2);
  u16* VB = (u16*)alloc((size_t)256 * NH * W_ * HD * 2);
  u16* OB = (u16*)alloc((size_t)2 * ROWS_ * C_ * 2);
  u16* WALL = (u16*)alloc((size_t)N_WALL * 2);
  float* PREP = (float*)alloc((size_t)12 * PREP_STRIDE * 4);
  float* ALPHA = (float*)alloc((size_t)256 * NH * W_ * 4);
  float* BETA = (float*)alloc((size_t)256 * NH * W_ * 4);
  float* GAMMA = (float*)alloc((size_t)256 * NH * W_ * 4);
  float* DELTA = (float*)alloc((size_t)256 * NH * W_ * 4);
  u16* XB = OB;   // alias — disjoint live ranges

  cvt_all_kernel<<<3136, 256, 0, stream>>>(feat_w, self_Wi, self_Wo, cross_Wi, cross_Wo, WALL);
  prep_kernel<<<dim3(12, 8), 256, 0, stream>>>(self_Wi, self_bi, cross_Wi, cross_bi, PREP);

  transpose_kernel<<<dim3(4, 64, 4), 256, 0, stream>>>(x_l, x_r, QB);
  gemm_plain<<<dim3(896, 2), 256, 0, stream>>>(QB, WALL + OFF_FEAT, feat_b, 5, XA);

  for (int l = 0; l < 6; ++l) {
    const u16* sWi = WALL + OFF_SWI + (size_t)l * 384 * 128;
    const u16* sWo = WALL + OFF_SWO + (size_t)l * 128 * 128;
    const u16* cWi = WALL + OFF_CWI + (size_t)l * 384 * 128;
    const u16* cWo = WALL + OFF_CWO + (size_t)l * 128 * 128;
    const float* sbi = self_bi + l * 384;
    const float* sbo = self_bo + l * 128;
    const float* cbi = cross_bi + l * 384;
    const float* cbo = cross_bo + l * 128;
    const float* ps = PREP + (size_t)(l * 2) * PREP_STRIDE;
    const float* pc = PREP + (size_t)(l * 2 + 1) * PREP_STRIDE;

    // --- self attention on xl AND xr: X = LN(X) (+tables+XB), qkv, attn, +=proj ---
    tab_kernel<<<1792, 256, 0, stream>>>(XA, ln_g, ln_b, ps, ps + 4096, ALPHA, BETA,
                                         ps + 2048, ps + 4112, GAMMA, DELTA, XB, 0);
    gemm_qkv_self<<<dim3(448, 3), 512, 0, stream>>>(XB, sWi, sbi, QB, KB, VB);
    attn_kernel<<<dim3(8, 256), 448, 0, stream>>>(QB, KB, VB, ALPHA, BETA, GAMMA, DELTA, OB);
    gemm_plain<<<dim3(896, 2), 256, 0, stream>>>(OB, sWo, sbo, 4, XA);

    // --- cross attention: q from xr, k/v from xl; X = LN(X) first ---
    tab_kernel<<<1792, 256, 0, stream>>>(XA, ln_g, ln_b, pc, pc + 4096, ALPHA, BETA,
                                         pc + 2048, pc + 4112, GAMMA, DELTA, XB, 1);
    // l==5: V (y=2) is dead — no attn launch follows and corresp reads QB/KB only.
    gemm_qkv_cross<<<dim3(224, (l < 5) ? 3 : 2), 512, 0, stream>>>(
        XB, XB + (size_t)ROWS_ * C_, cWi, cbi, QB, KB, VB);
    if (l < 5) {
      attn_kernel<<<dim3(8, 128), 448, 0, stream>>>(QB, KB, VB, ALPHA, BETA, GAMMA, DELTA, OB);
      gemm_plain<<<dim3(448, 2), 256, 0, stream>>>(OB, cWo, cbo, 4, XA);  // xl half only
    }
    // l == 5: attention output / x updates dead; corresp reads QB/KB + tables.
  }
  corresp_kernel<<<dim3(128, 2), 448, 0, stream>>>(QB, KB, ALPHA, BETA, GAMMA, DELTA,
                                                   (float*)d_out);
}

// Round 8
// 1211.625 us; speedup vs baseline: 1.0446x; 1.0446x over previous
//
#include <hip/hip_runtime.h>

typedef unsigned short u16;
typedef unsigned int u32;

#define W_ 224
#define H_ 128
#define C_ 128
#define NH 8
#define HD 16
#define ROWS_ (W_ * H_)          // 28672 rows per image
#define PREP_STRIDE 4128
#define KSTR 40
#define VSTR 232
#define TROWS 32                 // rows per tab_kernel block

typedef __bf16 bf16x8 __attribute__((ext_vector_type(8)));
typedef float f32x4 __attribute__((ext_vector_type(4)));

__device__ __forceinline__ u16 f2bf(float f) {
  u32 u = __float_as_uint(f);
  return (u16)((u + 0x7FFFu + ((u >> 16) & 1u)) >> 16);
}
// Packed RNE f32->bf16 pair: single v_cvt_pk_bf16_f32 (same rounding as f2bf).
__device__ __forceinline__ u32 cvtpk(float lo, float hi) {
  u32 r;
  asm("v_cvt_pk_bf16_f32 %0, %1, %2" : "=v"(r) : "v"(lo), "v"(hi));
  return r;
}
__device__ __forceinline__ float bflo(u32 u) { return __uint_as_float(u << 16); }
__device__ __forceinline__ float bfhi(u32 u) { return __uint_as_float(u & 0xFFFF0000u); }

#if __has_builtin(__builtin_amdgcn_exp2f)
#define EX2(x) __builtin_amdgcn_exp2f(x)
#else
#define EX2(x) __expf((x) * 0.6931471805599453f)
#endif

// ---------------------------------------------------------------------------
// Rank-1 PE decomposition prep: grid (12 s, 8 e-groups), LDS-staged, coalesced.
// ---------------------------------------------------------------------------
__global__ __launch_bounds__(256) void prep_kernel(
    const float* __restrict__ self_Wi, const float* __restrict__ self_bi,
    const float* __restrict__ cross_Wi, const float* __restrict__ cross_bi,
    float* __restrict__ prep) {
  __shared__ float Wq[16][132];
  __shared__ float Wk[16][132];
  __shared__ float u[128];
  __shared__ float Aq[16], Ak[16], bq[16], bk[16];
  const int s = blockIdx.x, e = blockIdx.y, l = s >> 1;
  const float* Wi = (s & 1) ? cross_Wi + (size_t)l * 384 * 128 : self_Wi + (size_t)l * 384 * 128;
  const float* bi = (s & 1) ? cross_bi + l * 384 : self_bi + l * 384;
  const int tid = threadIdx.x;
  if (tid < 128) {
    float ex = (float)(tid & ~1) * (1.f / 128.f);
    u[tid] = expf(-ex * logf(10000.f));
  }
  if (tid >= 128 && tid < 144) { int r = tid - 128; bq[r] = bi[e * 16 + r]; }
  if (tid >= 160 && tid < 176) { int r = tid - 160; bk[r] = bi[128 + e * 16 + r]; }
  for (int t = tid; t < 2048; t += 256) {
    int r = t >> 7, f = t & 127;
    Wq[r][f] = Wi[(size_t)(e * 16 + r) * 128 + f];
    Wk[r][f] = Wi[(size_t)(128 + e * 16 + r) * 128 + f];
  }
  __syncthreads();
  {
    const int grp = tid >> 3;
    const int lg = tid & 7;
    const float* row = (grp < 16) ? Wq[grp] : Wk[grp - 16];
    float a = 0.f;
#pragma unroll
    for (int i = 0; i < 16; ++i) a += row[lg * 16 + i] * u[lg * 16 + i];
    a += __shfl_xor(a, 1);
    a += __shfl_xor(a, 2);
    a += __shfl_xor(a, 4);
    if (lg == 0) {
      if (grp < 16) Aq[grp] = a;
      else          Ak[grp - 16] = a;
    }
  }
  __syncthreads();
  float* out = prep + (size_t)s * PREP_STRIDE;
  for (int t = tid; t < 512; t += 256) {
    int v = t >> 7, f = t & 127;
    float acc = 0.f;
#pragma unroll
    for (int c = 0; c < 16; ++c) {
      if (v == 0)      acc += Wq[c][f] * Ak[c];
      else if (v == 1) acc += Wq[c][f] * bk[c];
      else if (v == 2) acc += Wk[c][f] * Aq[c];
      else             acc += Wk[c][f] * bq[c];
    }
    out[v * 1024 + e * 128 + f] = acc * 0.25f;
  }
  if (tid < 4) {
    int v = tid;
    float acc = 0.f;
#pragma unroll
    for (int c = 0; c < 16; ++c) {
      if (v == 0)      acc += bq[c] * Ak[c];
      else if (v == 1) acc += bq[c] * bk[c];
      else if (v == 2) acc += bk[c] * Aq[c];
      else             acc += bk[c] * bq[c];
    }
    out[4096 + v * 8 + e] = acc * 0.25f;
  }
}

// ---------------------------------------------------------------------------
// Fused LN + affine-PE tables, 32 rows per block. X = LN(X) in place + bf16
// copy XB + fp32 alpha/beta/gamma/delta tables.
// R8: phase 2 is LDS-ISSUE-bound (1024 ds_read_b32/thread ~= 6000 cyc/wave,
// matches the observed 41us). Vectorize to ds_read_b128: ws stride 133->136
// (544B rows, 16B-aligned; bank=(2c+f)%32 -> 2-way = free), yr reads are
// same-address broadcasts. float4 lanes map onto the existing a0..a3
// accumulator striping -> identical op order, tables bit-identical.
// (R7's batched-LN kept: per-kernel neutral. MFMA phase-2 variant stays out
// per R4 tripwire.)
// ---------------------------------------------------------------------------
__global__ __launch_bounds__(256) void tab_kernel(
    float* __restrict__ x, const float* __restrict__ g,
    const float* __restrict__ b, const float* __restrict__ wq,
    const float* __restrict__ cq, float* __restrict__ outA, float* __restrict__ outB,
    const float* __restrict__ wk, const float* __restrict__ ck,
    float* __restrict__ outG, float* __restrict__ outD,
    u16* __restrict__ xb, int mode) {
  __shared__ float ys[TROWS][132];
  __shared__ float ws[32][136];
  const int tid = threadIdx.x;
  for (int t = tid; t < 2048; t += 256) ws[t >> 7][t & 127] = wq[t];
  for (int t = tid; t < 2048; t += 256) ws[16 + (t >> 7)][t & 127] = wk[t];
  const int wv = tid >> 6, lane = tid & 63;
  const int base = blockIdx.x * TROWS;
  {
    float2 gg = ((const float2*)g)[lane];
    float2 bb = ((const float2*)b)[lane];
    // batch the 8 row loads (independent, in flight together)
    float2 vv[8];
#pragma unroll
    for (int t = 0; t < 8; ++t) {
      const int r = wv * 8 + t;
      vv[t] = ((const float2*)(x + (size_t)(base + r) * 128))[lane];
    }
    // 8 independent reduce+write chains; compiler interleaves across VALU
#pragma unroll
    for (int t = 0; t < 8; ++t) {
      const int r = wv * 8 + t;
      float2 v = vv[t];
      float s1 = v.x + v.y, s2 = v.x * v.x + v.y * v.y;
#pragma unroll
      for (int k = 1; k < 64; k <<= 1) {
        s1 += __shfl_xor(s1, k);
        s2 += __shfl_xor(s2, k);
      }
      float mean = s1 * (1.f / 128.f);
      float var = s2 * (1.f / 128.f) - mean * mean;
      float rstd = rsqrtf(var + 1e-5f);
      float y0 = (v.x - mean) * rstd * gg.x + bb.x;
      float y1 = (v.y - mean) * rstd * gg.y + bb.y;
      ((float2*)(x + (size_t)(base + r) * 128))[lane] = make_float2(y0, y1);
      ((u32*)xb)[(size_t)(base + r) * 64 + lane] = cvtpk(y0, y1);
      ys[r][2 * lane] = y0;
      ys[r][2 * lane + 1] = y1;
    }
  }
  __syncthreads();
  const int c = tid & 31;
  const int rg = (tid >> 5) * 4;
  const int side = c >> 4, oo = c & 15;
  const float4* wrow4 = (const float4*)&ws[c][0];
  const int val = oo >> 3, e = oo & 7;
  const float cadd = side ? ck[val * 8 + e] : cq[val * 8 + e];
  float* dst = side ? (val ? outD : outG) : (val ? outB : outA);
#pragma unroll
  for (int rr = 0; rr < 4; ++rr) {
    const int p = base + rg + rr;
    const int half = (p >= ROWS_) ? 1 : 0;
    const int ploc = p - half * ROWS_;
    const bool active = (mode == 0) || (half ? (side == 0) : (side == 1));
    if (active) {
      const float4* yr4 = (const float4*)&ys[rg + rr][0];
      float a0 = 0.f, a1 = 0.f, a2 = 0.f, a3 = 0.f;
#pragma unroll 8
      for (int f4 = 0; f4 < 32; ++f4) {
        float4 y = yr4[f4];
        float4 w = wrow4[f4];
        a0 += y.x * w.x;
        a1 += y.y * w.y;
        a2 += y.z * w.z;
        a3 += y.w * w.w;
      }
      float acc = (a0 + a1) + (a2 + a3);
      int i = ploc >> 7, blow = ploc & 127;
      int b_out = (mode == 0) ? half * 128 + blow : blow;
      dst[((size_t)(b_out * 8 + e)) * 224 + i] = acc + cadd;
    }
  }
}

// ---------------------------------------------------------------------------
// Plain 64x64-tile bf16 MFMA GEMM (bf16 A input) — R3-verified version.
// mode 4: fout += acc + bias (out-proj residual); mode 5: fout = acc + bias.
// ---------------------------------------------------------------------------
__global__ __launch_bounds__(256) void gemm_plain(
    const u16* __restrict__ A, const u16* __restrict__ B,
    const float* __restrict__ bias, int mode, float* __restrict__ fout) {
  __shared__ u16 As[64 * 136];
  __shared__ u16 Bs[64 * 136];
  const int tid = threadIdx.x;
  const int M0 = blockIdx.x * 64, N0 = blockIdx.y * 64;
  const uint4* Ag = (const uint4*)(A + (size_t)M0 * 128);
  const uint4* Bg = (const uint4*)(B + (size_t)N0 * 128);
  for (int t = tid; t < 1024; t += 256) {
    int row = t >> 4, cc = t & 15;
    *(uint4*)&As[row * 136 + cc * 8] = Ag[row * 16 + cc];
  }
  for (int t = tid; t < 1024; t += 256) {
    int row = t >> 4, cc = t & 15;
    *(uint4*)&Bs[row * 136 + cc * 8] = Bg[row * 16 + cc];
  }
  __syncthreads();
  const int wave = tid >> 6, lane = tid & 63;
  const int wm = (wave >> 1) * 32, wn = (wave & 1) * 32;
  const int lr = lane & 15, kq = (lane >> 4) * 8;
  f32x4 acc[2][2] = {};
#pragma unroll
  for (int ks = 0; ks < 4; ++ks) {
    int ko = ks * 32 + kq;
    bf16x8 a0 = *(const bf16x8*)&As[(wm + lr) * 136 + ko];
    bf16x8 a1 = *(const bf16x8*)&As[(wm + 16 + lr) * 136 + ko];
    bf16x8 b0 = *(const bf16x8*)&Bs[(wn + lr) * 136 + ko];
    bf16x8 b1 = *(const bf16x8*)&Bs[(wn + 16 + lr) * 136 + ko];
    acc[0][0] = __builtin_amdgcn_mfma_f32_16x16x32_bf16(a0, b0, acc[0][0], 0, 0, 0);
    acc[0][1] = __builtin_amdgcn_mfma_f32_16x16x32_bf16(a0, b1, acc[0][1], 0, 0, 0);
    acc[1][0] = __builtin_amdgcn_mfma_f32_16x16x32_bf16(a1, b0, acc[1][0], 0, 0, 0);
    acc[1][1] = __builtin_amdgcn_mfma_f32_16x16x32_bf16(a1, b1, acc[1][1], 0, 0, 0);
  }
  const int colq = lane & 15, rowq = (lane >> 4) * 4;
#pragma unroll
  for (int tm = 0; tm < 2; ++tm)
#pragma unroll
    for (int tn = 0; tn < 2; ++tn) {
#pragma unroll
      for (int r = 0; r < 4; ++r) {
        int row = M0 + wm + tm * 16 + rowq + r;
        int col = N0 + wn + tn * 16 + colq;
        float v = acc[tm][tn][r] + bias[col];
        if (mode == 4) fout[(size_t)row * 128 + col] += v;
        else           fout[(size_t)row * 128 + col] = v;
      }
    }
}

// ---------------------------------------------------------------------------
// Self QKV GEMM: 128x128 tiles, 512 threads (8 waves, each 64x32). A from XB.
// ---------------------------------------------------------------------------
__global__ __launch_bounds__(512) void gemm_qkv_self(
    const u16* __restrict__ X, const u16* __restrict__ Bw,
    const float* __restrict__ bias, u16* __restrict__ o0, u16* __restrict__ o1,
    u16* __restrict__ o2) {
  __shared__ u16 As[128 * 136];
  __shared__ u16 Bs[128 * 136];
  const int tid = threadIdx.x;
  const int M0 = blockIdx.x * 128, N0 = blockIdx.y * 128;
  {
    const uint4* Bg = (const uint4*)(Bw + (size_t)N0 * 128);
    const uint4* Ag = (const uint4*)(X + (size_t)M0 * 128);
    for (int t = tid; t < 2048; t += 512) {
      int row = t >> 4, cc = t & 15;
      *(uint4*)&As[row * 136 + cc * 8] = Ag[row * 16 + cc];
      *(uint4*)&Bs[row * 136 + cc * 8] = Bg[row * 16 + cc];
    }
  }
  __syncthreads();
  const int wave = tid >> 6, lane = tid & 63;
  const int wm = (wave >> 2) * 64, wn = (wave & 3) * 32;
  const int lr = lane & 15, kq = (lane >> 4) * 8;
  f32x4 acc[4][2] = {};
#pragma unroll
  for (int ks = 0; ks < 4; ++ks) {
    int ko = ks * 32 + kq;
    bf16x8 b0 = *(const bf16x8*)&Bs[(wn + lr) * 136 + ko];
    bf16x8 b1 = *(const bf16x8*)&Bs[(wn + 16 + lr) * 136 + ko];
#pragma unroll
    for (int tm = 0; tm < 4; ++tm) {
      bf16x8 a0 = *(const bf16x8*)&As[(wm + tm * 16 + lr) * 136 + ko];
      acc[tm][0] = __builtin_amdgcn_mfma_f32_16x16x32_bf16(a0, b0, acc[tm][0], 0, 0, 0);
      acc[tm][1] = __builtin_amdgcn_mfma_f32_16x16x32_bf16(a0, b1, acc[tm][1], 0, 0, 0);
    }
  }
  const int colq = lane & 15, rowq = (lane >> 4) * 4;
#pragma unroll
  for (int tm = 0; tm < 4; ++tm)
#pragma unroll
    for (int tn = 0; tn < 2; ++tn) {
#pragma unroll
      for (int r = 0; r < 4; ++r) {
        int row = M0 + wm + tm * 16 + rowq + r;
        int col = N0 + wn + tn * 16 + colq;
        float v = acc[tm][tn][r] + bias[col];
        int part = col >> 7;
        int cc = col & 127;
        int e = cc >> 4, c = cc & 15;
        int rloc = row, badd = 0;
        if (row >= ROWS_) { rloc = row - ROWS_; badd = 128; }
        int b = (rloc & 127) + badd, pos = rloc >> 7;
        size_t off = ((size_t)(b * NH + e) * W_ + pos) * HD + c;
        if (part == 0)      o0[off] = f2bf(v * 0.25f);
        else if (part == 1) o1[off] = f2bf(v);
        else                o2[off] = f2bf(v);
      }
    }
}

// ---------------------------------------------------------------------------
// Cross QKV GEMM: 128x128 tiles, 512 threads.
// y=0: q from Xr (*0.25); y=1: K from Xl; y=2: V from Xl.
// At l=5 launched with grid.y=2 (V dead: no attn launch, corresp reads Q/K).
// ---------------------------------------------------------------------------
__global__ __launch_bounds__(512) void gemm_qkv_cross(
    const u16* __restrict__ Xl, const u16* __restrict__ Xr,
    const u16* __restrict__ cWi, const float* __restrict__ cbi,
    u16* __restrict__ QB, u16* __restrict__ KB, u16* __restrict__ VB) {
  __shared__ u16 As[128 * 136];
  __shared__ u16 Bs[128 * 136];
  const int tid = threadIdx.x;
  const int M0 = blockIdx.x * 128;
  const int y = blockIdx.y;
  const u16* X = (y == 0) ? Xr : Xl;
  const u16* Bw = cWi + (size_t)y * 128 * 128;
  const float* bias = cbi + y * 128;
  {
    const uint4* Bg = (const uint4*)Bw;
    const uint4* Ag = (const uint4*)(X + (size_t)M0 * 128);
    for (int t = tid; t < 2048; t += 512) {
      int row = t >> 4, cc = t & 15;
      *(uint4*)&As[row * 136 + cc * 8] = Ag[row * 16 + cc];
      *(uint4*)&Bs[row * 136 + cc * 8] = Bg[row * 16 + cc];
    }
  }
  __syncthreads();
  const int wave = tid >> 6, lane = tid & 63;
  const int wm = (wave >> 2) * 64, wn = (wave & 3) * 32;
  const int lr = lane & 15, kq = (lane >> 4) * 8;
  f32x4 acc[4][2] = {};
#pragma unroll
  for (int ks = 0; ks < 4; ++ks) {
    int ko = ks * 32 + kq;
    bf16x8 b0 = *(const bf16x8*)&Bs[(wn + lr) * 136 + ko];
    bf16x8 b1 = *(const bf16x8*)&Bs[(wn + 16 + lr) * 136 + ko];
#pragma unroll
    for (int tm = 0; tm < 4; ++tm) {
      bf16x8 a0 = *(const bf16x8*)&As[(wm + tm * 16 + lr) * 136 + ko];
      acc[tm][0] = __builtin_amdgcn_mfma_f32_16x16x32_bf16(a0, b0, acc[tm][0], 0, 0, 0);
      acc[tm][1] = __builtin_amdgcn_mfma_f32_16x16x32_bf16(a0, b1, acc[tm][1], 0, 0, 0);
    }
  }
  u16* outp = (y == 0) ? QB : ((y == 1) ? KB : VB);
  const float scale = (y == 0) ? 0.25f : 1.f;
  const int colq = lane & 15, rowq = (lane >> 4) * 4;
#pragma unroll
  for (int tm = 0; tm < 4; ++tm)
#pragma unroll
    for (int tn = 0; tn < 2; ++tn) {
#pragma unroll
      for (int r = 0; r < 4; ++r) {
        int row = M0 + wm + tm * 16 + rowq + r;
        int col = wn + tn * 16 + colq;
        float v = (acc[tm][tn][r] + bias[col]) * scale;
        int e = col >> 4, c = col & 15;
        int b = row & 127, pos = row >> 7;
        outp[((size_t)(b * NH + e) * W_ + pos) * HD + c] = f2bf(v);
      }
    }
}

// ---------------------------------------------------------------------------
// MFMA flash attention per (head e, batch-row b). Two-pass softmax. P stays
// in registers (sigma-permuted V); exp2 with log2e folded into Q-side staging.
// ---------------------------------------------------------------------------
__global__ __launch_bounds__(448) void attn_kernel(
    const u16* __restrict__ qb, const u16* __restrict__ kb,
    const u16* __restrict__ vb, const float* __restrict__ ALPHA,
    const float* __restrict__ BETA, const float* __restrict__ GAMMA,
    const float* __restrict__ DELTA, u16* __restrict__ obuf) {
  __shared__ u16 Ksh[224 * KSTR];
  __shared__ u16 Qsh[224 * KSTR];
  __shared__ u16 Vt[16 * VSTR];
  const int e = blockIdx.x, b = blockIdx.y;
  const size_t hb = (size_t)(b * NH + e);
  const int tid = threadIdx.x;
  const u32 ONE = 0x3F80u;
  const float LOG2E = 1.4426950408889634f;

  if (tid < 224) {
    const int j = tid;
    const uint4* src = (const uint4*)(kb + (hb * W_ + j) * HD);
    uint4 a = src[0], b2 = src[1];
    *(uint4*)&Ksh[j * KSTR] = a;
    *(uint4*)&Ksh[j * KSTR + 8] = b2;
    float G = GAMMA[hb * 224 + j];
    float D = DELTA[hb * 224 + j];
    float jf = (float)j;
    float P = (G * jf + D) * LOG2E;
    u16 Phi = f2bf(P);
    float Plo = P - __uint_as_float((u32)Phi << 16);
    u32* ex = (u32*)&Ksh[j * KSTR + 16];
    ex[0] = (u32)f2bf(G * LOG2E) | ((u32)Phi << 16);
    ex[1] = (u32)f2bf(Plo) | ((u32)f2bf(jf) << 16);
    ex[2] = ONE | (ONE << 16);
#pragma unroll
    for (int z = 3; z < 12; ++z) ex[z] = 0;
    const uint4* vsrc = (const uint4*)(vb + (hb * W_ + j) * HD);
    uint4 va = vsrc[0], vb4 = vsrc[1];
    u32 w[8] = {va.x, va.y, va.z, va.w, vb4.x, vb4.y, vb4.z, vb4.w};
    // sigma-permuted column so PV A-fragments come straight from registers
    const int jl = j & 31;
    const int qcol = (j & ~31) | (((jl >> 2) & 3) << 3) | ((jl >> 4) << 2) | (jl & 3);
#pragma unroll
    for (int c = 0; c < 16; ++c)
      Vt[c * VSTR + qcol] = (c & 1) ? (u16)(w[c >> 1] >> 16) : (u16)(w[c >> 1] & 0xFFFF);
  } else {
    const int i = tid - 224;
    const uint4* src = (const uint4*)(qb + (hb * W_ + i) * HD);
    uint4 a = src[0], b2 = src[1];
    u32 qa[8] = {a.x, a.y, a.z, a.w, b2.x, b2.y, b2.z, b2.w};
#pragma unroll
    for (int t = 0; t < 8; ++t)
      qa[t] = cvtpk(bflo(qa[t]) * LOG2E, bfhi(qa[t]) * LOG2E);
    *(uint4*)&Qsh[i * KSTR] = make_uint4(qa[0], qa[1], qa[2], qa[3]);
    *(uint4*)&Qsh[i * KSTR + 8] = make_uint4(qa[4], qa[5], qa[6], qa[7]);
    float al = ALPHA[hb * 224 + i];
    float be = BETA[hb * 224 + i];
    float ifl = (float)i;
    float Q = (be - al * ifl) * LOG2E;
    u16 Qhi = f2bf(Q);
    float Qlo = Q - __uint_as_float((u32)Qhi << 16);
    u32* ex = (u32*)&Qsh[i * KSTR + 16];
    ex[0] = (u32)f2bf(-ifl) | (ONE << 16);
    ex[1] = ONE | ((u32)f2bf(al * LOG2E) << 16);
    ex[2] = (u32)Qhi | ((u32)f2bf(Qlo) << 16);
#pragma unroll
    for (int z = 3; z < 12; ++z) ex[z] = 0;
  }
  __syncthreads();

  const int wid = tid >> 6, lane = tid & 63;
  const int g = lane >> 4, li = lane & 15;
  const int obase = (b & 128) ? ROWS_ : 0;
  const int blow = b & 127;

  for (int qt = wid * 2; qt < wid * 2 + 2; ++qt) {
    const int i0 = qt * 16;
    const bf16x8 Bq = *(const bf16x8*)&Qsh[(i0 + li) * KSTR + g * 8];
    f32x4 C[7][2];
#pragma unroll
    for (int js = 0; js < 7; ++js) {
      const bf16x8 A0 = *(const bf16x8*)&Ksh[(js * 32 + li) * KSTR + g * 8];
      const bf16x8 A1 = *(const bf16x8*)&Ksh[(js * 32 + 16 + li) * KSTR + g * 8];
      const f32x4 Z = {0.f, 0.f, 0.f, 0.f};
      C[js][0] = __builtin_amdgcn_mfma_f32_16x16x32_bf16(A0, Bq, Z, 0, 0, 0);
      C[js][1] = __builtin_amdgcn_mfma_f32_16x16x32_bf16(A1, Bq, Z, 0, 0, 0);
    }
    float m = -1e30f;
#pragma unroll
    for (int js = 0; js < 7; ++js)
#pragma unroll
      for (int h = 0; h < 2; ++h)
        m = fmaxf(m, fmaxf(fmaxf(C[js][h][0], C[js][h][1]), fmaxf(C[js][h][2], C[js][h][3])));
    m = fmaxf(m, __shfl_xor(m, 16));
    m = fmaxf(m, __shfl_xor(m, 32));
    f32x4 O = {0.f, 0.f, 0.f, 0.f};
    float lsum = 0.f;
#pragma unroll
    for (int js = 0; js < 7; ++js) {
      float p0 = EX2(C[js][0][0] - m), p1 = EX2(C[js][0][1] - m);
      float p2 = EX2(C[js][0][2] - m), p3 = EX2(C[js][0][3] - m);
      float p4 = EX2(C[js][1][0] - m), p5 = EX2(C[js][1][1] - m);
      float p6 = EX2(C[js][1][2] - m), p7 = EX2(C[js][1][3] - m);
      lsum += ((p0 + p1) + (p2 + p3)) + ((p4 + p5) + (p6 + p7));
      uint4 pu = make_uint4(cvtpk(p0, p1), cvtpk(p2, p3), cvtpk(p4, p5), cvtpk(p6, p7));
      const bf16x8 Ap = __builtin_bit_cast(bf16x8, pu);
      const bf16x8 Bv = *(const bf16x8*)&Vt[li * VSTR + js * 32 + g * 8];
      O = __builtin_amdgcn_mfma_f32_16x16x32_bf16(Ap, Bv, O, 0, 0, 0);
    }
    lsum += __shfl_xor(lsum, 16);
    lsum += __shfl_xor(lsum, 32);
#pragma unroll
    for (int r = 0; r < 4; ++r) {
      const float lr = __shfl(lsum, g * 4 + r);
      const int irow = i0 + g * 4 + r;
      obuf[((size_t)(obase + irow * 128 + blow)) * C_ + e * HD + li] = f2bf(O[r] * (1.f / lr));
    }
  }
}

// Gather x_l/x_r[b][c][h][w] -> bf16 rows p = img*28672 + w*128 + h*2 + b.
__global__ __launch_bounds__(256) void transpose_kernel(const float* __restrict__ x_l,
                                                        const float* __restrict__ x_r,
                                                        u16* __restrict__ xT) {
  __shared__ float tile[128][57];
  const int wt = blockIdx.x * 56, hi = blockIdx.y;
  const int img = blockIdx.z >> 1, bi = blockIdx.z & 1;
  const float* x = img ? x_r : x_l;
  const int wave = threadIdx.x >> 6, lane = threadIdx.x & 63;
  for (int c = wave; c < 128; c += 4) {
    if (lane < 56)
      tile[c][lane] = x[(((size_t)bi * 128 + c) * 64 + hi) * 224 + wt + lane];
  }
  __syncthreads();
  u32* dst = (u32*)xT;
  for (int w = wave; w < 56; w += 4) {
    int p = img * ROWS_ + (wt + w) * 128 + hi * 2 + bi;
    float a = tile[lane * 2][w], b2 = tile[lane * 2 + 1][w];
    dst[(size_t)p * 64 + lane] = (u32)f2bf(a) | ((u32)f2bf(b2) << 16);
  }
}

// ---------------------------------------------------------------------------
// Final soft-argmax, MFMA version.
// ---------------------------------------------------------------------------
__global__ __launch_bounds__(448) void corresp_kernel(
    const u16* __restrict__ qb, const u16* __restrict__ kb,
    const float* __restrict__ ALPHA, const float* __restrict__ BETA,
    const float* __restrict__ GAMMA, const float* __restrict__ DELTA,
    float* __restrict__ out) {
  __shared__ u16 Ksh[224 * 136];   // 60,928 B
  __shared__ float Gs[224], Ds[224];
  const int b = blockIdx.x, tid = threadIdx.x;
  if (tid < 224) {
    const int j = tid;
#pragma unroll
    for (int e = 0; e < 8; ++e) {
      const uint4* src = (const uint4*)(kb + ((size_t)(b * 8 + e) * 224 + j) * 16);
      *(uint4*)&Ksh[j * 136 + e * 16] = src[0];
      *(uint4*)&Ksh[j * 136 + e * 16 + 8] = src[1];
    }
    float gs = 0.f, ds = 0.f;
#pragma unroll
    for (int e = 0; e < 8; ++e) {
      gs += GAMMA[((size_t)(b * 8 + e)) * 224 + j];
      ds += DELTA[((size_t)(b * 8 + e)) * 224 + j];
    }
    Gs[j] = gs;
    Ds[j] = ds;
  }
  __syncthreads();
  const int wid = tid >> 6, lane = tid & 63;
  const int g = lane >> 4, li = lane & 15;
  const int i = blockIdx.y * 112 + wid * 16 + li;
  bf16x8 Bq[4];
#pragma unroll
  for (int ks = 0; ks < 4; ++ks) {
    const int e2 = ks * 2 + (g >> 1), c0 = (g & 1) * 8;
    Bq[ks] = *(const bf16x8*)&qb[((size_t)(b * 8 + e2) * 224 + i) * 16 + c0];
  }
  f32x4 C[14];
#pragma unroll
  for (int js = 0; js < 14; ++js) {
    f32x4 acc = {0.f, 0.f, 0.f, 0.f};
#pragma unroll
    for (int ks = 0; ks < 4; ++ks) {
      const bf16x8 A = *(const bf16x8*)&Ksh[(js * 16 + li) * 136 + ks * 32 + g * 8];
      acc = __builtin_amdgcn_mfma_f32_16x16x32_bf16(A, Bq[ks], acc, 0, 0, 0);
    }
    C[js] = acc;
  }
  float ai = 0.f, bi_ = 0.f;
#pragma unroll
  for (int e = 0; e < 8; ++e) {
    ai += ALPHA[((size_t)(b * 8 + e)) * 224 + i];
    bi_ += BETA[((size_t)(b * 8 + e)) * 224 + i];
  }
  const float ifl = (float)i;
  float m = -1e30f;
#pragma unroll
  for (int js = 0; js < 14; ++js) {
#pragma unroll
    for (int r = 0; r < 4; ++r) {
      const int j = js * 16 + g * 4 + r;
      float s = C[js][r] + ((float)j - ifl) * (ai + Gs[j]) + bi_ + Ds[j];
      C[js][r] = s;
      m = fmaxf(m, s);
    }
  }
  m = fmaxf(m, __shfl_xor(m, 16));
  m = fmaxf(m, __shfl_xor(m, 32));
  float l = 0.f, wj = 0.f;
#pragma unroll
  for (int js = 0; js < 14; ++js) {
#pragma unroll
    for (int r = 0; r < 4; ++r) {
      const float p = __expf(C[js][r] - m);
      l += p;
      wj += p * (float)(js * 16 + g * 4 + r);
    }
  }
  l += __shfl_xor(l, 16);
  l += __shfl_xor(l, 32);
  wj += __shfl_xor(wj, 16);
  wj += __shfl_xor(wj, 32);
  if (g == 0) out[(size_t)b * 224 + i] = ifl - wj / fmaxf(l, 1e-30f);
}

// Single-launch conversion of all five weight tensors to one bf16 buffer.
#define OFF_FEAT 0
#define OFF_SWI 16384
#define OFF_SWO 311296
#define OFF_CWI 409600
#define OFF_CWO 704512
#define N_WALL 802816
__global__ __launch_bounds__(256) void cvt_all_kernel(
    const float* __restrict__ feat_w, const float* __restrict__ self_Wi,
    const float* __restrict__ self_Wo, const float* __restrict__ cross_Wi,
    const float* __restrict__ cross_Wo, u16* __restrict__ dst) {
  int idx = blockIdx.x * 256 + threadIdx.x;
  if (idx >= N_WALL) return;
  float v;
  if (idx < OFF_SWI)       v = feat_w[idx];
  else if (idx < OFF_SWO)  v = self_Wi[idx - OFF_SWI];
  else if (idx < OFF_CWI)  v = self_Wo[idx - OFF_SWO];
  else if (idx < OFF_CWO)  v = cross_Wi[idx - OFF_CWI];
  else                     v = cross_Wo[idx - OFF_CWO];
  dst[idx] = f2bf(v);
}

extern "C" void kernel_launch(void* const* d_in, const int* in_sizes, int n_in,
                              void* d_out, int out_size, void* d_ws, size_t ws_size,
                              hipStream_t stream) {
  (void)in_sizes; (void)n_in; (void)out_size; (void)ws_size;
  const float* x_l = (const float*)d_in[0];
  const float* x_r = (const float*)d_in[1];
  const float* feat_w = (const float*)d_in[2];
  const float* feat_b = (const float*)d_in[3];
  const float* self_Wi = (const float*)d_in[4];
  const float* self_bi = (const float*)d_in[5];
  const float* self_Wo = (const float*)d_in[6];
  const float* self_bo = (const float*)d_in[7];
  const float* cross_Wi = (const float*)d_in[8];
  const float* cross_bi = (const float*)d_in[9];
  const float* cross_Wo = (const float*)d_in[10];
  const float* cross_bo = (const float*)d_in[11];
  const float* ln_g = (const float*)d_in[12];
  const float* ln_b = (const float*)d_in[13];

  char* ws = (char*)d_ws;
  size_t off = 0;
  auto alloc = [&](size_t bytes) {
    char* p = ws + off;
    off += (bytes + 255) & ~(size_t)255;
    return p;
  };
  // Total ~97 MB — under the R6-proven ~112 MB budget. XB aliases OB:
  // XB live range is tab->qkv, OB live range is attn->out-proj (disjoint).
  float* XA = (float*)alloc((size_t)2 * ROWS_ * C_ * 4);   // residual (in-place LN)
  u16* QB = (u16*)alloc((size_t)256 * NH * W_ * HD * 2);   // also XT scratch
  u16* KB = (u16*)alloc((size_t)256 * NH * W_ * HD * 2);
  u16* VB = (u16*)alloc((size_t)256 * NH * W_ * HD * 2);
  u16* OB = (u16*)alloc((size_t)2 * ROWS_ * C_ * 2);
  u16* WALL = (u16*)alloc((size_t)N_WALL * 2);
  float* PREP = (float*)alloc((size_t)12 * PREP_STRIDE * 4);
  float* ALPHA = (float*)alloc((size_t)256 * NH * W_ * 4);
  float* BETA = (float*)alloc((size_t)256 * NH * W_ * 4);
  float* GAMMA = (float*)alloc((size_t)256 * NH * W_ * 4);
  float* DELTA = (float*)alloc((size_t)256 * NH * W_ * 4);
  u16* XB = OB;   // alias — disjoint live ranges

  cvt_all_kernel<<<3136, 256, 0, stream>>>(feat_w, self_Wi, self_Wo, cross_Wi, cross_Wo, WALL);
  prep_kernel<<<dim3(12, 8), 256, 0, stream>>>(self_Wi, self_bi, cross_Wi, cross_bi, PREP);

  transpose_kernel<<<dim3(4, 64, 4), 256, 0, stream>>>(x_l, x_r, QB);
  gemm_plain<<<dim3(896, 2), 256, 0, stream>>>(QB, WALL + OFF_FEAT, feat_b, 5, XA);

  for (int l = 0; l < 6; ++l) {
    const u16* sWi = WALL + OFF_SWI + (size_t)l * 384 * 128;
    const u16* sWo = WALL + OFF_SWO + (size_t)l * 128 * 128;
    const u16* cWi = WALL + OFF_CWI + (size_t)l * 384 * 128;
    const u16* cWo = WALL + OFF_CWO + (size_t)l * 128 * 128;
    const float* sbi = self_bi + l * 384;
    const float* sbo = self_bo + l * 128;
    const float* cbi = cross_bi + l * 384;
    const float* cbo = cross_bo + l * 128;
    const float* ps = PREP + (size_t)(l * 2) * PREP_STRIDE;
    const float* pc = PREP + (size_t)(l * 2 + 1) * PREP_STRIDE;

    // --- self attention on xl AND xr: X = LN(X) (+tables+XB), qkv, attn, +=proj ---
    tab_kernel<<<1792, 256, 0, stream>>>(XA, ln_g, ln_b, ps, ps + 4096, ALPHA, BETA,
                                         ps + 2048, ps + 4112, GAMMA, DELTA, XB, 0);
    gemm_qkv_self<<<dim3(448, 3), 512, 0, stream>>>(XB, sWi, sbi, QB, KB, VB);
    attn_kernel<<<dim3(8, 256), 448, 0, stream>>>(QB, KB, VB, ALPHA, BETA, GAMMA, DELTA, OB);
    gemm_plain<<<dim3(896, 2), 256, 0, stream>>>(OB, sWo, sbo, 4, XA);

    // --- cross attention: q from xr, k/v from xl; X = LN(X) first ---
    tab_kernel<<<1792, 256, 0, stream>>>(XA, ln_g, ln_b, pc, pc + 4096, ALPHA, BETA,
                                         pc + 2048, pc + 4112, GAMMA, DELTA, XB, 1);
    // l==5: V (y=2) is dead — no attn launch follows and corresp reads QB/KB only.
    gemm_qkv_cross<<<dim3(224, (l < 5) ? 3 : 2), 512, 0, stream>>>(
        XB, XB + (size_t)ROWS_ * C_, cWi, cbi, QB, KB, VB);
    if (l < 5) {
      attn_kernel<<<dim3(8, 128), 448, 0, stream>>>(QB, KB, VB, ALPHA, BETA, GAMMA, DELTA, OB);
      gemm_plain<<<dim3(448, 2), 256, 0, stream>>>(OB, cWo, cbo, 4, XA);  // xl half only
    }
    // l == 5: attention output / x updates dead; corresp reads QB/KB + tables.
  }
  corresp_kernel<<<dim3(128, 2), 448, 0, stream>>>(QB, KB, ALPHA, BETA, GAMMA, DELTA,
                                                   (float*)d_out);
}

// Round 9
// 1167.971 us; speedup vs baseline: 1.0836x; 1.0374x over previous
//
#include <hip/hip_runtime.h>

typedef unsigned short u16;
typedef unsigned int u32;

#define W_ 224
#define H_ 128
#define C_ 128
#define NH 8
#define HD 16
#define ROWS_ (W_ * H_)          // 28672 rows per image
#define PREP_STRIDE 4128
#define KSTR 40
#define VSTR 232
#define TROWS 32                 // rows per tab_kernel block

typedef __bf16 bf16x8 __attribute__((ext_vector_type(8)));
typedef float f32x4 __attribute__((ext_vector_type(4)));

__device__ __forceinline__ u16 f2bf(float f) {
  u32 u = __float_as_uint(f);
  return (u16)((u + 0x7FFFu + ((u >> 16) & 1u)) >> 16);
}
// Packed RNE f32->bf16 pair: single v_cvt_pk_bf16_f32 (same rounding as f2bf).
__device__ __forceinline__ u32 cvtpk(float lo, float hi) {
  u32 r;
  asm("v_cvt_pk_bf16_f32 %0, %1, %2" : "=v"(r) : "v"(lo), "v"(hi));
  return r;
}
__device__ __forceinline__ float bflo(u32 u) { return __uint_as_float(u << 16); }
__device__ __forceinline__ float bfhi(u32 u) { return __uint_as_float(u & 0xFFFF0000u); }

#if __has_builtin(__builtin_amdgcn_exp2f)
#define EX2(x) __builtin_amdgcn_exp2f(x)
#else
#define EX2(x) __expf((x) * 0.6931471805599453f)
#endif

// ---------------------------------------------------------------------------
// Rank-1 PE decomposition prep: grid (12 s, 8 e-groups), LDS-staged, coalesced.
// ---------------------------------------------------------------------------
__global__ __launch_bounds__(256) void prep_kernel(
    const float* __restrict__ self_Wi, const float* __restrict__ self_bi,
    const float* __restrict__ cross_Wi, const float* __restrict__ cross_bi,
    float* __restrict__ prep) {
  __shared__ float Wq[16][132];
  __shared__ float Wk[16][132];
  __shared__ float u[128];
  __shared__ float Aq[16], Ak[16], bq[16], bk[16];
  const int s = blockIdx.x, e = blockIdx.y, l = s >> 1;
  const float* Wi = (s & 1) ? cross_Wi + (size_t)l * 384 * 128 : self_Wi + (size_t)l * 384 * 128;
  const float* bi = (s & 1) ? cross_bi + l * 384 : self_bi + l * 384;
  const int tid = threadIdx.x;
  if (tid < 128) {
    float ex = (float)(tid & ~1) * (1.f / 128.f);
    u[tid] = expf(-ex * logf(10000.f));
  }
  if (tid >= 128 && tid < 144) { int r = tid - 128; bq[r] = bi[e * 16 + r]; }
  if (tid >= 160 && tid < 176) { int r = tid - 160; bk[r] = bi[128 + e * 16 + r]; }
  for (int t = tid; t < 2048; t += 256) {
    int r = t >> 7, f = t & 127;
    Wq[r][f] = Wi[(size_t)(e * 16 + r) * 128 + f];
    Wk[r][f] = Wi[(size_t)(128 + e * 16 + r) * 128 + f];
  }
  __syncthreads();
  {
    const int grp = tid >> 3;
    const int lg = tid & 7;
    const float* row = (grp < 16) ? Wq[grp] : Wk[grp - 16];
    float a = 0.f;
#pragma unroll
    for (int i = 0; i < 16; ++i) a += row[lg * 16 + i] * u[lg * 16 + i];
    a += __shfl_xor(a, 1);
    a += __shfl_xor(a, 2);
    a += __shfl_xor(a, 4);
    if (lg == 0) {
      if (grp < 16) Aq[grp] = a;
      else          Ak[grp - 16] = a;
    }
  }
  __syncthreads();
  float* out = prep + (size_t)s * PREP_STRIDE;
  for (int t = tid; t < 512; t += 256) {
    int v = t >> 7, f = t & 127;
    float acc = 0.f;
#pragma unroll
    for (int c = 0; c < 16; ++c) {
      if (v == 0)      acc += Wq[c][f] * Ak[c];
      else if (v == 1) acc += Wq[c][f] * bk[c];
      else if (v == 2) acc += Wk[c][f] * Aq[c];
      else             acc += Wk[c][f] * bq[c];
    }
    out[v * 1024 + e * 128 + f] = acc * 0.25f;
  }
  if (tid < 4) {
    int v = tid;
    float acc = 0.f;
#pragma unroll
    for (int c = 0; c < 16; ++c) {
      if (v == 0)      acc += bq[c] * Ak[c];
      else if (v == 1) acc += bq[c] * bk[c];
      else if (v == 2) acc += bk[c] * Aq[c];
      else             acc += bk[c] * bq[c];
    }
    out[4096 + v * 8 + e] = acc * 0.25f;
  }
}

// ---------------------------------------------------------------------------
// Fused LN + affine-PE tables, 32 rows per block. X = LN(X) in place + bf16
// copy XB + fp32 alpha/beta/gamma/delta tables.
// R9: phase 2 still LDS-issue-bound after R8 (28 waves/CU x 256 b128 x 12cyc
// = 36us, matches measurement). Two fixes, both bit-identical:
//  (a) loop swap f4-outer/rr-inner: w read once per f4 (not 4x) -> 160
//      LDS reads/thread (-37%). Per-accumulator f4 order still ascending.
//  (b) ws stride 136->132: b128 bank-quad (2c+f4)%8 (8-way) -> (c+f4)%8
//      (minimal 4-way); 528B rows still 16B-aligned.
// ---------------------------------------------------------------------------
__global__ __launch_bounds__(256) void tab_kernel(
    float* __restrict__ x, const float* __restrict__ g,
    const float* __restrict__ b, const float* __restrict__ wq,
    const float* __restrict__ cq, float* __restrict__ outA, float* __restrict__ outB,
    const float* __restrict__ wk, const float* __restrict__ ck,
    float* __restrict__ outG, float* __restrict__ outD,
    u16* __restrict__ xb, int mode) {
  __shared__ float ys[TROWS][132];
  __shared__ float ws[32][132];
  const int tid = threadIdx.x;
  for (int t = tid; t < 2048; t += 256) ws[t >> 7][t & 127] = wq[t];
  for (int t = tid; t < 2048; t += 256) ws[16 + (t >> 7)][t & 127] = wk[t];
  const int wv = tid >> 6, lane = tid & 63;
  const int base = blockIdx.x * TROWS;
  {
    float2 gg = ((const float2*)g)[lane];
    float2 bb = ((const float2*)b)[lane];
    // batch the 8 row loads (independent, in flight together)
    float2 vv[8];
#pragma unroll
    for (int t = 0; t < 8; ++t) {
      const int r = wv * 8 + t;
      vv[t] = ((const float2*)(x + (size_t)(base + r) * 128))[lane];
    }
    // 8 independent reduce+write chains; compiler interleaves across VALU
#pragma unroll
    for (int t = 0; t < 8; ++t) {
      const int r = wv * 8 + t;
      float2 v = vv[t];
      float s1 = v.x + v.y, s2 = v.x * v.x + v.y * v.y;
#pragma unroll
      for (int k = 1; k < 64; k <<= 1) {
        s1 += __shfl_xor(s1, k);
        s2 += __shfl_xor(s2, k);
      }
      float mean = s1 * (1.f / 128.f);
      float var = s2 * (1.f / 128.f) - mean * mean;
      float rstd = rsqrtf(var + 1e-5f);
      float y0 = (v.x - mean) * rstd * gg.x + bb.x;
      float y1 = (v.y - mean) * rstd * gg.y + bb.y;
      ((float2*)(x + (size_t)(base + r) * 128))[lane] = make_float2(y0, y1);
      ((u32*)xb)[(size_t)(base + r) * 64 + lane] = cvtpk(y0, y1);
      ys[r][2 * lane] = y0;
      ys[r][2 * lane + 1] = y1;
    }
  }
  __syncthreads();
  const int c = tid & 31;
  const int rg = (tid >> 5) * 4;
  const int side = c >> 4, oo = c & 15;
  const float4* wrow4 = (const float4*)&ws[c][0];
  const int val = oo >> 3, e = oo & 7;
  const float cadd = side ? ck[val * 8 + e] : cq[val * 8 + e];
  float* dst = side ? (val ? outD : outG) : (val ? outB : outA);
  // rows rg..rg+3 never straddle ROWS_ (28672 = 896*32): half/active uniform
  const int pbase = base + rg;
  const int half = (pbase >= ROWS_) ? 1 : 0;
  const bool active = (mode == 0) || (half ? (side == 0) : (side == 1));
  if (active) {
    const float4* yr0 = (const float4*)&ys[rg][0];
    const float4* yr1 = (const float4*)&ys[rg + 1][0];
    const float4* yr2 = (const float4*)&ys[rg + 2][0];
    const float4* yr3 = (const float4*)&ys[rg + 3][0];
    float4 sA = {0.f, 0.f, 0.f, 0.f}, sB = sA, sC = sA, sD = sA;
#pragma unroll 4
    for (int f4 = 0; f4 < 32; ++f4) {
      float4 w = wrow4[f4];
      float4 yA = yr0[f4], yB = yr1[f4], yC = yr2[f4], yD = yr3[f4];
      sA.x += yA.x * w.x; sA.y += yA.y * w.y; sA.z += yA.z * w.z; sA.w += yA.w * w.w;
      sB.x += yB.x * w.x; sB.y += yB.y * w.y; sB.z += yB.z * w.z; sB.w += yB.w * w.w;
      sC.x += yC.x * w.x; sC.y += yC.y * w.y; sC.z += yC.z * w.z; sC.w += yC.w * w.w;
      sD.x += yD.x * w.x; sD.y += yD.y * w.y; sD.z += yD.z * w.z; sD.w += yD.w * w.w;
    }
    const float accs[4] = {
        (sA.x + sA.y) + (sA.z + sA.w), (sB.x + sB.y) + (sB.z + sB.w),
        (sC.x + sC.y) + (sC.z + sC.w), (sD.x + sD.y) + (sD.z + sD.w)};
#pragma unroll
    for (int rr = 0; rr < 4; ++rr) {
      const int ploc = pbase + rr - half * ROWS_;
      int i = ploc >> 7, blow = ploc & 127;
      int b_out = (mode == 0) ? half * 128 + blow : blow;
      dst[((size_t)(b_out * 8 + e)) * 224 + i] = accs[rr] + cadd;
    }
  }
}

// ---------------------------------------------------------------------------
// Plain 64x64-tile bf16 MFMA GEMM (bf16 A input) — R3-verified version.
// mode 4: fout += acc + bias (out-proj residual); mode 5: fout = acc + bias.
// ---------------------------------------------------------------------------
__global__ __launch_bounds__(256) void gemm_plain(
    const u16* __restrict__ A, const u16* __restrict__ B,
    const float* __restrict__ bias, int mode, float* __restrict__ fout) {
  __shared__ u16 As[64 * 136];
  __shared__ u16 Bs[64 * 136];
  const int tid = threadIdx.x;
  const int M0 = blockIdx.x * 64, N0 = blockIdx.y * 64;
  const uint4* Ag = (const uint4*)(A + (size_t)M0 * 128);
  const uint4* Bg = (const uint4*)(B + (size_t)N0 * 128);
  for (int t = tid; t < 1024; t += 256) {
    int row = t >> 4, cc = t & 15;
    *(uint4*)&As[row * 136 + cc * 8] = Ag[row * 16 + cc];
  }
  for (int t = tid; t < 1024; t += 256) {
    int row = t >> 4, cc = t & 15;
    *(uint4*)&Bs[row * 136 + cc * 8] = Bg[row * 16 + cc];
  }
  __syncthreads();
  const int wave = tid >> 6, lane = tid & 63;
  const int wm = (wave >> 1) * 32, wn = (wave & 1) * 32;
  const int lr = lane & 15, kq = (lane >> 4) * 8;
  f32x4 acc[2][2] = {};
#pragma unroll
  for (int ks = 0; ks < 4; ++ks) {
    int ko = ks * 32 + kq;
    bf16x8 a0 = *(const bf16x8*)&As[(wm + lr) * 136 + ko];
    bf16x8 a1 = *(const bf16x8*)&As[(wm + 16 + lr) * 136 + ko];
    bf16x8 b0 = *(const bf16x8*)&Bs[(wn + lr) * 136 + ko];
    bf16x8 b1 = *(const bf16x8*)&Bs[(wn + 16 + lr) * 136 + ko];
    acc[0][0] = __builtin_amdgcn_mfma_f32_16x16x32_bf16(a0, b0, acc[0][0], 0, 0, 0);
    acc[0][1] = __builtin_amdgcn_mfma_f32_16x16x32_bf16(a0, b1, acc[0][1], 0, 0, 0);
    acc[1][0] = __builtin_amdgcn_mfma_f32_16x16x32_bf16(a1, b0, acc[1][0], 0, 0, 0);
    acc[1][1] = __builtin_amdgcn_mfma_f32_16x16x32_bf16(a1, b1, acc[1][1], 0, 0, 0);
  }
  const int colq = lane & 15, rowq = (lane >> 4) * 4;
#pragma unroll
  for (int tm = 0; tm < 2; ++tm)
#pragma unroll
    for (int tn = 0; tn < 2; ++tn) {
#pragma unroll
      for (int r = 0; r < 4; ++r) {
        int row = M0 + wm + tm * 16 + rowq + r;
        int col = N0 + wn + tn * 16 + colq;
        float v = acc[tm][tn][r] + bias[col];
        if (mode == 4) fout[(size_t)row * 128 + col] += v;
        else           fout[(size_t)row * 128 + col] = v;
      }
    }
}

// ---------------------------------------------------------------------------
// Self QKV GEMM: 128x128 tiles, 512 threads (8 waves, each 64x32). A from XB.
// ---------------------------------------------------------------------------
__global__ __launch_bounds__(512) void gemm_qkv_self(
    const u16* __restrict__ X, const u16* __restrict__ Bw,
    const float* __restrict__ bias, u16* __restrict__ o0, u16* __restrict__ o1,
    u16* __restrict__ o2) {
  __shared__ u16 As[128 * 136];
  __shared__ u16 Bs[128 * 136];
  const int tid = threadIdx.x;
  const int M0 = blockIdx.x * 128, N0 = blockIdx.y * 128;
  {
    const uint4* Bg = (const uint4*)(Bw + (size_t)N0 * 128);
    const uint4* Ag = (const uint4*)(X + (size_t)M0 * 128);
    for (int t = tid; t < 2048; t += 512) {
      int row = t >> 4, cc = t & 15;
      *(uint4*)&As[row * 136 + cc * 8] = Ag[row * 16 + cc];
      *(uint4*)&Bs[row * 136 + cc * 8] = Bg[row * 16 + cc];
    }
  }
  __syncthreads();
  const int wave = tid >> 6, lane = tid & 63;
  const int wm = (wave >> 2) * 64, wn = (wave & 3) * 32;
  const int lr = lane & 15, kq = (lane >> 4) * 8;
  f32x4 acc[4][2] = {};
#pragma unroll
  for (int ks = 0; ks < 4; ++ks) {
    int ko = ks * 32 + kq;
    bf16x8 b0 = *(const bf16x8*)&Bs[(wn + lr) * 136 + ko];
    bf16x8 b1 = *(const bf16x8*)&Bs[(wn + 16 + lr) * 136 + ko];
#pragma unroll
    for (int tm = 0; tm < 4; ++tm) {
      bf16x8 a0 = *(const bf16x8*)&As[(wm + tm * 16 + lr) * 136 + ko];
      acc[tm][0] = __builtin_amdgcn_mfma_f32_16x16x32_bf16(a0, b0, acc[tm][0], 0, 0, 0);
      acc[tm][1] = __builtin_amdgcn_mfma_f32_16x16x32_bf16(a0, b1, acc[tm][1], 0, 0, 0);
    }
  }
  const int colq = lane & 15, rowq = (lane >> 4) * 4;
#pragma unroll
  for (int tm = 0; tm < 4; ++tm)
#pragma unroll
    for (int tn = 0; tn < 2; ++tn) {
#pragma unroll
      for (int r = 0; r < 4; ++r) {
        int row = M0 + wm + tm * 16 + rowq + r;
        int col = N0 + wn + tn * 16 + colq;
        float v = acc[tm][tn][r] + bias[col];
        int part = col >> 7;
        int cc = col & 127;
        int e = cc >> 4, c = cc & 15;
        int rloc = row, badd = 0;
        if (row >= ROWS_) { rloc = row - ROWS_; badd = 128; }
        int b = (rloc & 127) + badd, pos = rloc >> 7;
        size_t off = ((size_t)(b * NH + e) * W_ + pos) * HD + c;
        if (part == 0)      o0[off] = f2bf(v * 0.25f);
        else if (part == 1) o1[off] = f2bf(v);
        else                o2[off] = f2bf(v);
      }
    }
}

// ---------------------------------------------------------------------------
// Cross QKV GEMM: 128x128 tiles, 512 threads.
// y=0: q from Xr (*0.25); y=1: K from Xl; y=2: V from Xl.
// At l=5 launched with grid.y=2 (V dead: no attn launch, corresp reads Q/K).
// ---------------------------------------------------------------------------
__global__ __launch_bounds__(512) void gemm_qkv_cross(
    const u16* __restrict__ Xl, const u16* __restrict__ Xr,
    const u16* __restrict__ cWi, const float* __restrict__ cbi,
    u16* __restrict__ QB, u16* __restrict__ KB, u16* __restrict__ VB) {
  __shared__ u16 As[128 * 136];
  __shared__ u16 Bs[128 * 136];
  const int tid = threadIdx.x;
  const int M0 = blockIdx.x * 128;
  const int y = blockIdx.y;
  const u16* X = (y == 0) ? Xr : Xl;
  const u16* Bw = cWi + (size_t)y * 128 * 128;
  const float* bias = cbi + y * 128;
  {
    const uint4* Bg = (const uint4*)Bw;
    const uint4* Ag = (const uint4*)(X + (size_t)M0 * 128);
    for (int t = tid; t < 2048; t += 512) {
      int row = t >> 4, cc = t & 15;
      *(uint4*)&As[row * 136 + cc * 8] = Ag[row * 16 + cc];
      *(uint4*)&Bs[row * 136 + cc * 8] = Bg[row * 16 + cc];
    }
  }
  __syncthreads();
  const int wave = tid >> 6, lane = tid & 63;
  const int wm = (wave >> 2) * 64, wn = (wave & 3) * 32;
  const int lr = lane & 15, kq = (lane >> 4) * 8;
  f32x4 acc[4][2] = {};
#pragma unroll
  for (int ks = 0; ks < 4; ++ks) {
    int ko = ks * 32 + kq;
    bf16x8 b0 = *(const bf16x8*)&Bs[(wn + lr) * 136 + ko];
    bf16x8 b1 = *(const bf16x8*)&Bs[(wn + 16 + lr) * 136 + ko];
#pragma unroll
    for (int tm = 0; tm < 4; ++tm) {
      bf16x8 a0 = *(const bf16x8*)&As[(wm + tm * 16 + lr) * 136 + ko];
      acc[tm][0] = __builtin_amdgcn_mfma_f32_16x16x32_bf16(a0, b0, acc[tm][0], 0, 0, 0);
      acc[tm][1] = __builtin_amdgcn_mfma_f32_16x16x32_bf16(a0, b1, acc[tm][1], 0, 0, 0);
    }
  }
  u16* outp = (y == 0) ? QB : ((y == 1) ? KB : VB);
  const float scale = (y == 0) ? 0.25f : 1.f;
  const int colq = lane & 15, rowq = (lane >> 4) * 4;
#pragma unroll
  for (int tm = 0; tm < 4; ++tm)
#pragma unroll
    for (int tn = 0; tn < 2; ++tn) {
#pragma unroll
      for (int r = 0; r < 4; ++r) {
        int row = M0 + wm + tm * 16 + rowq + r;
        int col = wn + tn * 16 + colq;
        float v = (acc[tm][tn][r] + bias[col]) * scale;
        int e = col >> 4, c = col & 15;
        int b = row & 127, pos = row >> 7;
        outp[((size_t)(b * NH + e) * W_ + pos) * HD + c] = f2bf(v);
      }
    }
}

// ---------------------------------------------------------------------------
// MFMA flash attention per (head e, batch-row b). Two-pass softmax. P stays
// in registers (sigma-permuted V); exp2 with log2e folded into Q-side staging.
// ---------------------------------------------------------------------------
__global__ __launch_bounds__(448) void attn_kernel(
    const u16* __restrict__ qb, const u16* __restrict__ kb,
    const u16* __restrict__ vb, const float* __restrict__ ALPHA,
    const float* __restrict__ BETA, const float* __restrict__ GAMMA,
    const float* __restrict__ DELTA, u16* __restrict__ obuf) {
  __shared__ u16 Ksh[224 * KSTR];
  __shared__ u16 Qsh[224 * KSTR];
  __shared__ u16 Vt[16 * VSTR];
  const int e = blockIdx.x, b = blockIdx.y;
  const size_t hb = (size_t)(b * NH + e);
  const int tid = threadIdx.x;
  const u32 ONE = 0x3F80u;
  const float LOG2E = 1.4426950408889634f;

  if (tid < 224) {
    const int j = tid;
    const uint4* src = (const uint4*)(kb + (hb * W_ + j) * HD);
    uint4 a = src[0], b2 = src[1];
    *(uint4*)&Ksh[j * KSTR] = a;
    *(uint4*)&Ksh[j * KSTR + 8] = b2;
    float G = GAMMA[hb * 224 + j];
    float D = DELTA[hb * 224 + j];
    float jf = (float)j;
    float P = (G * jf + D) * LOG2E;
    u16 Phi = f2bf(P);
    float Plo = P - __uint_as_float((u32)Phi << 16);
    u32* ex = (u32*)&Ksh[j * KSTR + 16];
    ex[0] = (u32)f2bf(G * LOG2E) | ((u32)Phi << 16);
    ex[1] = (u32)f2bf(Plo) | ((u32)f2bf(jf) << 16);
    ex[2] = ONE | (ONE << 16);
#pragma unroll
    for (int z = 3; z < 12; ++z) ex[z] = 0;
    const uint4* vsrc = (const uint4*)(vb + (hb * W_ + j) * HD);
    uint4 va = vsrc[0], vb4 = vsrc[1];
    u32 w[8] = {va.x, va.y, va.z, va.w, vb4.x, vb4.y, vb4.z, vb4.w};
    // sigma-permuted column so PV A-fragments come straight from registers
    const int jl = j & 31;
    const int qcol = (j & ~31) | (((jl >> 2) & 3) << 3) | ((jl >> 4) << 2) | (jl & 3);
#pragma unroll
    for (int c = 0; c < 16; ++c)
      Vt[c * VSTR + qcol] = (c & 1) ? (u16)(w[c >> 1] >> 16) : (u16)(w[c >> 1] & 0xFFFF);
  } else {
    const int i = tid - 224;
    const uint4* src = (const uint4*)(qb + (hb * W_ + i) * HD);
    uint4 a = src[0], b2 = src[1];
    u32 qa[8] = {a.x, a.y, a.z, a.w, b2.x, b2.y, b2.z, b2.w};
#pragma unroll
    for (int t = 0; t < 8; ++t)
      qa[t] = cvtpk(bflo(qa[t]) * LOG2E, bfhi(qa[t]) * LOG2E);
    *(uint4*)&Qsh[i * KSTR] = make_uint4(qa[0], qa[1], qa[2], qa[3]);
    *(uint4*)&Qsh[i * KSTR + 8] = make_uint4(qa[4], qa[5], qa[6], qa[7]);
    float al = ALPHA[hb * 224 + i];
    float be = BETA[hb * 224 + i];
    float ifl = (float)i;
    float Q = (be - al * ifl) * LOG2E;
    u16 Qhi = f2bf(Q);
    float Qlo = Q - __uint_as_float((u32)Qhi << 16);
    u32* ex = (u32*)&Qsh[i * KSTR + 16];
    ex[0] = (u32)f2bf(-ifl) | (ONE << 16);
    ex[1] = ONE | ((u32)f2bf(al * LOG2E) << 16);
    ex[2] = (u32)Qhi | ((u32)f2bf(Qlo) << 16);
#pragma unroll
    for (int z = 3; z < 12; ++z) ex[z] = 0;
  }
  __syncthreads();

  const int wid = tid >> 6, lane = tid & 63;
  const int g = lane >> 4, li = lane & 15;
  const int obase = (b & 128) ? ROWS_ : 0;
  const int blow = b & 127;

  for (int qt = wid * 2; qt < wid * 2 + 2; ++qt) {
    const int i0 = qt * 16;
    const bf16x8 Bq = *(const bf16x8*)&Qsh[(i0 + li) * KSTR + g * 8];
    f32x4 C[7][2];
#pragma unroll
    for (int js = 0; js < 7; ++js) {
      const bf16x8 A0 = *(const bf16x8*)&Ksh[(js * 32 + li) * KSTR + g * 8];
      const bf16x8 A1 = *(const bf16x8*)&Ksh[(js * 32 + 16 + li) * KSTR + g * 8];
      const f32x4 Z = {0.f, 0.f, 0.f, 0.f};
      C[js][0] = __builtin_amdgcn_mfma_f32_16x16x32_bf16(A0, Bq, Z, 0, 0, 0);
      C[js][1] = __builtin_amdgcn_mfma_f32_16x16x32_bf16(A1, Bq, Z, 0, 0, 0);
    }
    float m = -1e30f;
#pragma unroll
    for (int js = 0; js < 7; ++js)
#pragma unroll
      for (int h = 0; h < 2; ++h)
        m = fmaxf(m, fmaxf(fmaxf(C[js][h][0], C[js][h][1]), fmaxf(C[js][h][2], C[js][h][3])));
    m = fmaxf(m, __shfl_xor(m, 16));
    m = fmaxf(m, __shfl_xor(m, 32));
    f32x4 O = {0.f, 0.f, 0.f, 0.f};
    float lsum = 0.f;
#pragma unroll
    for (int js = 0; js < 7; ++js) {
      float p0 = EX2(C[js][0][0] - m), p1 = EX2(C[js][0][1] - m);
      float p2 = EX2(C[js][0][2] - m), p3 = EX2(C[js][0][3] - m);
      float p4 = EX2(C[js][1][0] - m), p5 = EX2(C[js][1][1] - m);
      float p6 = EX2(C[js][1][2] - m), p7 = EX2(C[js][1][3] - m);
      lsum += ((p0 + p1) + (p2 + p3)) + ((p4 + p5) + (p6 + p7));
      uint4 pu = make_uint4(cvtpk(p0, p1), cvtpk(p2, p3), cvtpk(p4, p5), cvtpk(p6, p7));
      const bf16x8 Ap = __builtin_bit_cast(bf16x8, pu);
      const bf16x8 Bv = *(const bf16x8*)&Vt[li * VSTR + js * 32 + g * 8];
      O = __builtin_amdgcn_mfma_f32_16x16x32_bf16(Ap, Bv, O, 0, 0, 0);
    }
    lsum += __shfl_xor(lsum, 16);
    lsum += __shfl_xor(lsum, 32);
#pragma unroll
    for (int r = 0; r < 4; ++r) {
      const float lr = __shfl(lsum, g * 4 + r);
      const int irow = i0 + g * 4 + r;
      obuf[((size_t)(obase + irow * 128 + blow)) * C_ + e * HD + li] = f2bf(O[r] * (1.f / lr));
    }
  }
}

// Gather x_l/x_r[b][c][h][w] -> bf16 rows p = img*28672 + w*128 + h*2 + b.
__global__ __launch_bounds__(256) void transpose_kernel(const float* __restrict__ x_l,
                                                        const float* __restrict__ x_r,
                                                        u16* __restrict__ xT) {
  __shared__ float tile[128][57];
  const int wt = blockIdx.x * 56, hi = blockIdx.y;
  const int img = blockIdx.z >> 1, bi = blockIdx.z & 1;
  const float* x = img ? x_r : x_l;
  const int wave = threadIdx.x >> 6, lane = threadIdx.x & 63;
  for (int c = wave; c < 128; c += 4) {
    if (lane < 56)
      tile[c][lane] = x[(((size_t)bi * 128 + c) * 64 + hi) * 224 + wt + lane];
  }
  __syncthreads();
  u32* dst = (u32*)xT;
  for (int w = wave; w < 56; w += 4) {
    int p = img * ROWS_ + (wt + w) * 128 + hi * 2 + bi;
    float a = tile[lane * 2][w], b2 = tile[lane * 2 + 1][w];
    dst[(size_t)p * 64 + lane] = (u32)f2bf(a) | ((u32)f2bf(b2) << 16);
  }
}

// ---------------------------------------------------------------------------
// Final soft-argmax, MFMA version.
// ---------------------------------------------------------------------------
__global__ __launch_bounds__(448) void corresp_kernel(
    const u16* __restrict__ qb, const u16* __restrict__ kb,
    const float* __restrict__ ALPHA, const float* __restrict__ BETA,
    const float* __restrict__ GAMMA, const float* __restrict__ DELTA,
    float* __restrict__ out) {
  __shared__ u16 Ksh[224 * 136];   // 60,928 B
  __shared__ float Gs[224], Ds[224];
  const int b = blockIdx.x, tid = threadIdx.x;
  if (tid < 224) {
    const int j = tid;
#pragma unroll
    for (int e = 0; e < 8; ++e) {
      const uint4* src = (const uint4*)(kb + ((size_t)(b * 8 + e) * 224 + j) * 16);
      *(uint4*)&Ksh[j * 136 + e * 16] = src[0];
      *(uint4*)&Ksh[j * 136 + e * 16 + 8] = src[1];
    }
    float gs = 0.f, ds = 0.f;
#pragma unroll
    for (int e = 0; e < 8; ++e) {
      gs += GAMMA[((size_t)(b * 8 + e)) * 224 + j];
      ds += DELTA[((size_t)(b * 8 + e)) * 224 + j];
    }
    Gs[j] = gs;
    Ds[j] = ds;
  }
  __syncthreads();
  const int wid = tid >> 6, lane = tid & 63;
  const int g = lane >> 4, li = lane & 15;
  const int i = blockIdx.y * 112 + wid * 16 + li;
  bf16x8 Bq[4];
#pragma unroll
  for (int ks = 0; ks < 4; ++ks) {
    const int e2 = ks * 2 + (g >> 1), c0 = (g & 1) * 8;
    Bq[ks] = *(const bf16x8*)&qb[((size_t)(b * 8 + e2) * 224 + i) * 16 + c0];
  }
  f32x4 C[14];
#pragma unroll
  for (int js = 0; js < 14; ++js) {
    f32x4 acc = {0.f, 0.f, 0.f, 0.f};
#pragma unroll
    for (int ks = 0; ks < 4; ++ks) {
      const bf16x8 A = *(const bf16x8*)&Ksh[(js * 16 + li) * 136 + ks * 32 + g * 8];
      acc = __builtin_amdgcn_mfma_f32_16x16x32_bf16(A, Bq[ks], acc, 0, 0, 0);
    }
    C[js] = acc;
  }
  float ai = 0.f, bi_ = 0.f;
#pragma unroll
  for (int e = 0; e < 8; ++e) {
    ai += ALPHA[((size_t)(b * 8 + e)) * 224 + i];
    bi_ += BETA[((size_t)(b * 8 + e)) * 224 + i];
  }
  const float ifl = (float)i;
  float m = -1e30f;
#pragma unroll
  for (int js = 0; js < 14; ++js) {
#pragma unroll
    for (int r = 0; r < 4; ++r) {
      const int j = js * 16 + g * 4 + r;
      float s = C[js][r] + ((float)j - ifl) * (ai + Gs[j]) + bi_ + Ds[j];
      C[js][r] = s;
      m = fmaxf(m, s);
    }
  }
  m = fmaxf(m, __shfl_xor(m, 16));
  m = fmaxf(m, __shfl_xor(m, 32));
  float l = 0.f, wj = 0.f;
#pragma unroll
  for (int js = 0; js < 14; ++js) {
#pragma unroll
    for (int r = 0; r < 4; ++r) {
      const float p = __expf(C[js][r] - m);
      l += p;
      wj += p * (float)(js * 16 + g * 4 + r);
    }
  }
  l += __shfl_xor(l, 16);
  l += __shfl_xor(l, 32);
  wj += __shfl_xor(wj, 16);
  wj += __shfl_xor(wj, 32);
  if (g == 0) out[(size_t)b * 224 + i] = ifl - wj / fmaxf(l, 1e-30f);
}

// Single-launch conversion of all five weight tensors to one bf16 buffer.
#define OFF_FEAT 0
#define OFF_SWI 16384
#define OFF_SWO 311296
#define OFF_CWI 409600
#define OFF_CWO 704512
#define N_WALL 802816
__global__ __launch_bounds__(256) void cvt_all_kernel(
    const float* __restrict__ feat_w, const float* __restrict__ self_Wi,
    const float* __restrict__ self_Wo, const float* __restrict__ cross_Wi,
    const float* __restrict__ cross_Wo, u16* __restrict__ dst) {
  int idx = blockIdx.x * 256 + threadIdx.x;
  if (idx >= N_WALL) return;
  float v;
  if (idx < OFF_SWI)       v = feat_w[idx];
  else if (idx < OFF_SWO)  v = self_Wi[idx - OFF_SWI];
  else if (idx < OFF_CWI)  v = self_Wo[idx - OFF_SWO];
  else if (idx < OFF_CWO)  v = cross_Wi[idx - OFF_CWI];
  else                     v = cross_Wo[idx - OFF_CWO];
  dst[idx] = f2bf(v);
}

extern "C" void kernel_launch(void* const* d_in, const int* in_sizes, int n_in,
                              void* d_out, int out_size, void* d_ws, size_t ws_size,
                              hipStream_t stream) {
  (void)in_sizes; (void)n_in; (void)out_size; (void)ws_size;
  const float* x_l = (const float*)d_in[0];
  const float* x_r = (const float*)d_in[1];
  const float* feat_w = (const float*)d_in[2];
  const float* feat_b = (const float*)d_in[3];
  const float* self_Wi = (const float*)d_in[4];
  const float* self_bi = (const float*)d_in[5];
  const float* self_Wo = (const float*)d_in[6];
  const float* self_bo = (const float*)d_in[7];
  const float* cross_Wi = (const float*)d_in[8];
  const float* cross_bi = (const float*)d_in[9];
  const float* cross_Wo = (const float*)d_in[10];
  const float* cross_bo = (const float*)d_in[11];
  const float* ln_g = (const float*)d_in[12];
  const float* ln_b = (const float*)d_in[13];

  char* ws = (char*)d_ws;
  size_t off = 0;
  auto alloc = [&](size_t bytes) {
    char* p = ws + off;
    off += (bytes + 255) & ~(size_t)255;
    return p;
  };
  // Total ~97 MB — under the R6-proven ~112 MB budget. XB aliases OB:
  // XB live range is tab->qkv, OB live range is attn->out-proj (disjoint).
  float* XA = (float*)alloc((size_t)2 * ROWS_ * C_ * 4);   // residual (in-place LN)
  u16* QB = (u16*)alloc((size_t)256 * NH * W_ * HD * 2);   // also XT scratch
  u16* KB = (u16*)alloc((size_t)256 * NH * W_ * HD * 2);
  u16* VB = (u16*)alloc((size_t)256 * NH * W_ * HD * 2);
  u16* OB = (u16*)alloc((size_t)2 * ROWS_ * C_ * 2);
  u16* WALL = (u16*)alloc((size_t)N_WALL * 2);
  float* PREP = (float*)alloc((size_t)12 * PREP_STRIDE * 4);
  float* ALPHA = (float*)alloc((size_t)256 * NH * W_ * 4);
  float* BETA = (float*)alloc((size_t)256 * NH * W_ * 4);
  float* GAMMA = (float*)alloc((size_t)256 * NH * W_ * 4);
  float* DELTA = (float*)alloc((size_t)256 * NH * W_ * 4);
  u16* XB = OB;   // alias — disjoint live ranges

  cvt_all_kernel<<<3136, 256, 0, stream>>>(feat_w, self_Wi, self_Wo, cross_Wi, cross_Wo, WALL);
  prep_kernel<<<dim3(12, 8), 256, 0, stream>>>(self_Wi, self_bi, cross_Wi, cross_bi, PREP);

  transpose_kernel<<<dim3(4, 64, 4), 256, 0, stream>>>(x_l, x_r, QB);
  gemm_plain<<<dim3(896, 2), 256, 0, stream>>>(QB, WALL + OFF_FEAT, feat_b, 5, XA);

  for (int l = 0; l < 6; ++l) {
    const u16* sWi = WALL + OFF_SWI + (size_t)l * 384 * 128;
    const u16* sWo = WALL + OFF_SWO + (size_t)l * 128 * 128;
    const u16* cWi = WALL + OFF_CWI + (size_t)l * 384 * 128;
    const u16* cWo = WALL + OFF_CWO + (size_t)l * 128 * 128;
    const float* sbi = self_bi + l * 384;
    const float* sbo = self_bo + l * 128;
    const float* cbi = cross_bi + l * 384;
    const float* cbo = cross_bo + l * 128;
    const float* ps = PREP + (size_t)(l * 2) * PREP_STRIDE;
    const float* pc = PREP + (size_t)(l * 2 + 1) * PREP_STRIDE;

    // --- self attention on xl AND xr: X = LN(X) (+tables+XB), qkv, attn, +=proj ---
    tab_kernel<<<1792, 256, 0, stream>>>(XA, ln_g, ln_b, ps, ps + 4096, ALPHA, BETA,
                                         ps + 2048, ps + 4112, GAMMA, DELTA, XB, 0);
    gemm_qkv_self<<<dim3(448, 3), 512, 0, stream>>>(XB, sWi, sbi, QB, KB, VB);
    attn_kernel<<<dim3(8, 256), 448, 0, stream>>>(QB, KB, VB, ALPHA, BETA, GAMMA, DELTA, OB);
    gemm_plain<<<dim3(896, 2), 256, 0, stream>>>(OB, sWo, sbo, 4, XA);

    // --- cross attention: q from xr, k/v from xl; X = LN(X) first ---
    tab_kernel<<<1792, 256, 0, stream>>>(XA, ln_g, ln_b, pc, pc + 4096, ALPHA, BETA,
                                         pc + 2048, pc + 4112, GAMMA, DELTA, XB, 1);
    // l==5: V (y=2) is dead — no attn launch follows and corresp reads QB/KB only.
    gemm_qkv_cross<<<dim3(224, (l < 5) ? 3 : 2), 512, 0, stream>>>(
        XB, XB + (size_t)ROWS_ * C_, cWi, cbi, QB, KB, VB);
    if (l < 5) {
      attn_kernel<<<dim3(8, 128), 448, 0, stream>>>(QB, KB, VB, ALPHA, BETA, GAMMA, DELTA, OB);
      gemm_plain<<<dim3(448, 2), 256, 0, stream>>>(OB, cWo, cbo, 4, XA);  // xl half only
    }
    // l == 5: attention output / x updates dead; corresp reads QB/KB + tables.
  }
  corresp_kernel<<<dim3(128, 2), 448, 0, stream>>>(QB, KB, ALPHA, BETA, GAMMA, DELTA,
                                                   (float*)d_out);
}

// Round 10
// 1143.659 us; speedup vs baseline: 1.1066x; 1.0213x over previous
//
#include <hip/hip_runtime.h>

typedef unsigned short u16;
typedef unsigned int u32;

#define W_ 224
#define H_ 128
#define C_ 128
#define NH 8
#define HD 16
#define ROWS_ (W_ * H_)          // 28672 rows per image
#define PREP_STRIDE 4128
#define KSTR 40
#define VSTR 232
#define TROWS 32                 // rows per tab_kernel block

typedef __bf16 bf16x8 __attribute__((ext_vector_type(8)));
typedef float f32x4 __attribute__((ext_vector_type(4)));

__device__ __forceinline__ u16 f2bf(float f) {
  u32 u = __float_as_uint(f);
  return (u16)((u + 0x7FFFu + ((u >> 16) & 1u)) >> 16);
}
// Packed RNE f32->bf16 pair: single v_cvt_pk_bf16_f32 (same rounding as f2bf).
__device__ __forceinline__ u32 cvtpk(float lo, float hi) {
  u32 r;
  asm("v_cvt_pk_bf16_f32 %0, %1, %2" : "=v"(r) : "v"(lo), "v"(hi));
  return r;
}
__device__ __forceinline__ float bflo(u32 u) { return __uint_as_float(u << 16); }
__device__ __forceinline__ float bfhi(u32 u) { return __uint_as_float(u & 0xFFFF0000u); }

#if __has_builtin(__builtin_amdgcn_exp2f)
#define EX2(x) __builtin_amdgcn_exp2f(x)
#else
#define EX2(x) __expf((x) * 0.6931471805599453f)
#endif

// ---------------------------------------------------------------------------
// Rank-1 PE decomposition prep: grid (12 s, 8 e-groups), LDS-staged, coalesced.
// ---------------------------------------------------------------------------
__global__ __launch_bounds__(256) void prep_kernel(
    const float* __restrict__ self_Wi, const float* __restrict__ self_bi,
    const float* __restrict__ cross_Wi, const float* __restrict__ cross_bi,
    float* __restrict__ prep) {
  __shared__ float Wq[16][132];
  __shared__ float Wk[16][132];
  __shared__ float u[128];
  __shared__ float Aq[16], Ak[16], bq[16], bk[16];
  const int s = blockIdx.x, e = blockIdx.y, l = s >> 1;
  const float* Wi = (s & 1) ? cross_Wi + (size_t)l * 384 * 128 : self_Wi + (size_t)l * 384 * 128;
  const float* bi = (s & 1) ? cross_bi + l * 384 : self_bi + l * 384;
  const int tid = threadIdx.x;
  if (tid < 128) {
    float ex = (float)(tid & ~1) * (1.f / 128.f);
    u[tid] = expf(-ex * logf(10000.f));
  }
  if (tid >= 128 && tid < 144) { int r = tid - 128; bq[r] = bi[e * 16 + r]; }
  if (tid >= 160 && tid < 176) { int r = tid - 160; bk[r] = bi[128 + e * 16 + r]; }
  for (int t = tid; t < 2048; t += 256) {
    int r = t >> 7, f = t & 127;
    Wq[r][f] = Wi[(size_t)(e * 16 + r) * 128 + f];
    Wk[r][f] = Wi[(size_t)(128 + e * 16 + r) * 128 + f];
  }
  __syncthreads();
  {
    const int grp = tid >> 3;
    const int lg = tid & 7;
    const float* row = (grp < 16) ? Wq[grp] : Wk[grp - 16];
    float a = 0.f;
#pragma unroll
    for (int i = 0; i < 16; ++i) a += row[lg * 16 + i] * u[lg * 16 + i];
    a += __shfl_xor(a, 1);
    a += __shfl_xor(a, 2);
    a += __shfl_xor(a, 4);
    if (lg == 0) {
      if (grp < 16) Aq[grp] = a;
      else          Ak[grp - 16] = a;
    }
  }
  __syncthreads();
  float* out = prep + (size_t)s * PREP_STRIDE;
  for (int t = tid; t < 512; t += 256) {
    int v = t >> 7, f = t & 127;
    float acc = 0.f;
#pragma unroll
    for (int c = 0; c < 16; ++c) {
      if (v == 0)      acc += Wq[c][f] * Ak[c];
      else if (v == 1) acc += Wq[c][f] * bk[c];
      else if (v == 2) acc += Wk[c][f] * Aq[c];
      else             acc += Wk[c][f] * bq[c];
    }
    out[v * 1024 + e * 128 + f] = acc * 0.25f;
  }
  if (tid < 4) {
    int v = tid;
    float acc = 0.f;
#pragma unroll
    for (int c = 0; c < 16; ++c) {
      if (v == 0)      acc += bq[c] * Ak[c];
      else if (v == 1) acc += bq[c] * bk[c];
      else if (v == 2) acc += bk[c] * Aq[c];
      else             acc += bk[c] * bq[c];
    }
    out[4096 + v * 8 + e] = acc * 0.25f;
  }
}

// ---------------------------------------------------------------------------
// Fused LN + affine-PE tables, 32 rows per block. X = LN(X) in place + bf16
// copy XB + fp32 alpha/beta/gamma/delta tables.
// R10: phase-2 thread remap 4x1 -> 2x2 (rows x cols per thread). Per-thread
// LDS issue = (rows+cols)*32 b128 reads for rows*cols=4 outputs: 160 -> 128
// (-20%). Col pair {2c2,2c2+1} shares side/val/dst (even start); row pair
// stays in one half (32-row-aligned blocks). Per-output dot order and final
// combine unchanged -> tables bit-identical.
// ---------------------------------------------------------------------------
__global__ __launch_bounds__(256) void tab_kernel(
    float* __restrict__ x, const float* __restrict__ g,
    const float* __restrict__ b, const float* __restrict__ wq,
    const float* __restrict__ cq, float* __restrict__ outA, float* __restrict__ outB,
    const float* __restrict__ wk, const float* __restrict__ ck,
    float* __restrict__ outG, float* __restrict__ outD,
    u16* __restrict__ xb, int mode) {
  __shared__ float ys[TROWS][132];
  __shared__ float ws[32][132];
  const int tid = threadIdx.x;
  for (int t = tid; t < 2048; t += 256) ws[t >> 7][t & 127] = wq[t];
  for (int t = tid; t < 2048; t += 256) ws[16 + (t >> 7)][t & 127] = wk[t];
  const int wv = tid >> 6, lane = tid & 63;
  const int base = blockIdx.x * TROWS;
  {
    float2 gg = ((const float2*)g)[lane];
    float2 bb = ((const float2*)b)[lane];
    // batch the 8 row loads (independent, in flight together)
    float2 vv[8];
#pragma unroll
    for (int t = 0; t < 8; ++t) {
      const int r = wv * 8 + t;
      vv[t] = ((const float2*)(x + (size_t)(base + r) * 128))[lane];
    }
    // 8 independent reduce+write chains; compiler interleaves across VALU
#pragma unroll
    for (int t = 0; t < 8; ++t) {
      const int r = wv * 8 + t;
      float2 v = vv[t];
      float s1 = v.x + v.y, s2 = v.x * v.x + v.y * v.y;
#pragma unroll
      for (int k = 1; k < 64; k <<= 1) {
        s1 += __shfl_xor(s1, k);
        s2 += __shfl_xor(s2, k);
      }
      float mean = s1 * (1.f / 128.f);
      float var = s2 * (1.f / 128.f) - mean * mean;
      float rstd = rsqrtf(var + 1e-5f);
      float y0 = (v.x - mean) * rstd * gg.x + bb.x;
      float y1 = (v.y - mean) * rstd * gg.y + bb.y;
      ((float2*)(x + (size_t)(base + r) * 128))[lane] = make_float2(y0, y1);
      ((u32*)xb)[(size_t)(base + r) * 64 + lane] = cvtpk(y0, y1);
      ys[r][2 * lane] = y0;
      ys[r][2 * lane + 1] = y1;
    }
  }
  __syncthreads();
  // 2x2 remap: thread (c2 = tid&15, rg2 = tid>>4) owns cols {2c2,2c2+1},
  // rows {2rg2, 2rg2+1}. 16x16 threads cover 32x32 outputs.
  const int c2 = tid & 15;
  const int rg2 = tid >> 4;
  const int c0 = c2 * 2;
  const int row0 = rg2 * 2;
  const int side = c0 >> 4;              // same for both cols (even start)
  const int val = (c0 & 15) >> 3;        // same for both cols
  const int e0 = c0 & 7, e1 = (c0 + 1) & 7;
  const float cadd0 = side ? ck[val * 8 + e0] : cq[val * 8 + e0];
  const float cadd1 = side ? ck[val * 8 + e1] : cq[val * 8 + e1];
  float* dst = side ? (val ? outD : outG) : (val ? outB : outA);
  // rows never straddle ROWS_ (28672 = 896*32): half uniform per block
  const int pbase = base + row0;
  const int half = (pbase >= ROWS_) ? 1 : 0;
  const bool active = (mode == 0) || (half ? (side == 0) : (side == 1));
  if (active) {
    const float4* w0 = (const float4*)&ws[c0][0];
    const float4* w1 = (const float4*)&ws[c0 + 1][0];
    const float4* y0 = (const float4*)&ys[row0][0];
    const float4* y1 = (const float4*)&ys[row0 + 1][0];
    float4 s00 = {0.f, 0.f, 0.f, 0.f}, s01 = s00, s10 = s00, s11 = s00;
#pragma unroll 4
    for (int f4 = 0; f4 < 32; ++f4) {
      float4 wa = w0[f4], wb = w1[f4];
      float4 ya = y0[f4], yb = y1[f4];
      s00.x += ya.x * wa.x; s00.y += ya.y * wa.y; s00.z += ya.z * wa.z; s00.w += ya.w * wa.w;
      s01.x += ya.x * wb.x; s01.y += ya.y * wb.y; s01.z += ya.z * wb.z; s01.w += ya.w * wb.w;
      s10.x += yb.x * wa.x; s10.y += yb.y * wa.y; s10.z += yb.z * wa.z; s10.w += yb.w * wa.w;
      s11.x += yb.x * wb.x; s11.y += yb.y * wb.y; s11.z += yb.z * wb.z; s11.w += yb.w * wb.w;
    }
    const float a00 = (s00.x + s00.y) + (s00.z + s00.w);
    const float a01 = (s01.x + s01.y) + (s01.z + s01.w);
    const float a10 = (s10.x + s10.y) + (s10.z + s10.w);
    const float a11 = (s11.x + s11.y) + (s11.z + s11.w);
#pragma unroll
    for (int rr = 0; rr < 2; ++rr) {
      const int ploc = pbase + rr - half * ROWS_;
      const int i = ploc >> 7, blow = ploc & 127;
      const int b_out = (mode == 0) ? half * 128 + blow : blow;
      const float v0 = (rr == 0) ? a00 : a10;
      const float v1 = (rr == 0) ? a01 : a11;
      dst[((size_t)(b_out * 8 + e0)) * 224 + i] = v0 + cadd0;
      dst[((size_t)(b_out * 8 + e1)) * 224 + i] = v1 + cadd1;
    }
  }
}

// ---------------------------------------------------------------------------
// Plain 64x64-tile bf16 MFMA GEMM (bf16 A input) — R3-verified version.
// mode 4: fout += acc + bias (out-proj residual); mode 5: fout = acc + bias.
// ---------------------------------------------------------------------------
__global__ __launch_bounds__(256) void gemm_plain(
    const u16* __restrict__ A, const u16* __restrict__ B,
    const float* __restrict__ bias, int mode, float* __restrict__ fout) {
  __shared__ u16 As[64 * 136];
  __shared__ u16 Bs[64 * 136];
  const int tid = threadIdx.x;
  const int M0 = blockIdx.x * 64, N0 = blockIdx.y * 64;
  const uint4* Ag = (const uint4*)(A + (size_t)M0 * 128);
  const uint4* Bg = (const uint4*)(B + (size_t)N0 * 128);
  for (int t = tid; t < 1024; t += 256) {
    int row = t >> 4, cc = t & 15;
    *(uint4*)&As[row * 136 + cc * 8] = Ag[row * 16 + cc];
  }
  for (int t = tid; t < 1024; t += 256) {
    int row = t >> 4, cc = t & 15;
    *(uint4*)&Bs[row * 136 + cc * 8] = Bg[row * 16 + cc];
  }
  __syncthreads();
  const int wave = tid >> 6, lane = tid & 63;
  const int wm = (wave >> 1) * 32, wn = (wave & 1) * 32;
  const int lr = lane & 15, kq = (lane >> 4) * 8;
  f32x4 acc[2][2] = {};
#pragma unroll
  for (int ks = 0; ks < 4; ++ks) {
    int ko = ks * 32 + kq;
    bf16x8 a0 = *(const bf16x8*)&As[(wm + lr) * 136 + ko];
    bf16x8 a1 = *(const bf16x8*)&As[(wm + 16 + lr) * 136 + ko];
    bf16x8 b0 = *(const bf16x8*)&Bs[(wn + lr) * 136 + ko];
    bf16x8 b1 = *(const bf16x8*)&Bs[(wn + 16 + lr) * 136 + ko];
    acc[0][0] = __builtin_amdgcn_mfma_f32_16x16x32_bf16(a0, b0, acc[0][0], 0, 0, 0);
    acc[0][1] = __builtin_amdgcn_mfma_f32_16x16x32_bf16(a0, b1, acc[0][1], 0, 0, 0);
    acc[1][0] = __builtin_amdgcn_mfma_f32_16x16x32_bf16(a1, b0, acc[1][0], 0, 0, 0);
    acc[1][1] = __builtin_amdgcn_mfma_f32_16x16x32_bf16(a1, b1, acc[1][1], 0, 0, 0);
  }
  const int colq = lane & 15, rowq = (lane >> 4) * 4;
#pragma unroll
  for (int tm = 0; tm < 2; ++tm)
#pragma unroll
    for (int tn = 0; tn < 2; ++tn) {
#pragma unroll
      for (int r = 0; r < 4; ++r) {
        int row = M0 + wm + tm * 16 + rowq + r;
        int col = N0 + wn + tn * 16 + colq;
        float v = acc[tm][tn][r] + bias[col];
        if (mode == 4) fout[(size_t)row * 128 + col] += v;
        else           fout[(size_t)row * 128 + col] = v;
      }
    }
}

// ---------------------------------------------------------------------------
// Self QKV GEMM: 128x128 tiles, 512 threads (8 waves, each 64x32). A from XB.
// ---------------------------------------------------------------------------
__global__ __launch_bounds__(512) void gemm_qkv_self(
    const u16* __restrict__ X, const u16* __restrict__ Bw,
    const float* __restrict__ bias, u16* __restrict__ o0, u16* __restrict__ o1,
    u16* __restrict__ o2) {
  __shared__ u16 As[128 * 136];
  __shared__ u16 Bs[128 * 136];
  const int tid = threadIdx.x;
  const int M0 = blockIdx.x * 128, N0 = blockIdx.y * 128;
  {
    const uint4* Bg = (const uint4*)(Bw + (size_t)N0 * 128);
    const uint4* Ag = (const uint4*)(X + (size_t)M0 * 128);
    for (int t = tid; t < 2048; t += 512) {
      int row = t >> 4, cc = t & 15;
      *(uint4*)&As[row * 136 + cc * 8] = Ag[row * 16 + cc];
      *(uint4*)&Bs[row * 136 + cc * 8] = Bg[row * 16 + cc];
    }
  }
  __syncthreads();
  const int wave = tid >> 6, lane = tid & 63;
  const int wm = (wave >> 2) * 64, wn = (wave & 3) * 32;
  const int lr = lane & 15, kq = (lane >> 4) * 8;
  f32x4 acc[4][2] = {};
#pragma unroll
  for (int ks = 0; ks < 4; ++ks) {
    int ko = ks * 32 + kq;
    bf16x8 b0 = *(const bf16x8*)&Bs[(wn + lr) * 136 + ko];
    bf16x8 b1 = *(const bf16x8*)&Bs[(wn + 16 + lr) * 136 + ko];
#pragma unroll
    for (int tm = 0; tm < 4; ++tm) {
      bf16x8 a0 = *(const bf16x8*)&As[(wm + tm * 16 + lr) * 136 + ko];
      acc[tm][0] = __builtin_amdgcn_mfma_f32_16x16x32_bf16(a0, b0, acc[tm][0], 0, 0, 0);
      acc[tm][1] = __builtin_amdgcn_mfma_f32_16x16x32_bf16(a0, b1, acc[tm][1], 0, 0, 0);
    }
  }
  const int colq = lane & 15, rowq = (lane >> 4) * 4;
#pragma unroll
  for (int tm = 0; tm < 4; ++tm)
#pragma unroll
    for (int tn = 0; tn < 2; ++tn) {
#pragma unroll
      for (int r = 0; r < 4; ++r) {
        int row = M0 + wm + tm * 16 + rowq + r;
        int col = N0 + wn + tn * 16 + colq;
        float v = acc[tm][tn][r] + bias[col];
        int part = col >> 7;
        int cc = col & 127;
        int e = cc >> 4, c = cc & 15;
        int rloc = row, badd = 0;
        if (row >= ROWS_) { rloc = row - ROWS_; badd = 128; }
        int b = (rloc & 127) + badd, pos = rloc >> 7;
        size_t off = ((size_t)(b * NH + e) * W_ + pos) * HD + c;
        if (part == 0)      o0[off] = f2bf(v * 0.25f);
        else if (part == 1) o1[off] = f2bf(v);
        else                o2[off] = f2bf(v);
      }
    }
}

// ---------------------------------------------------------------------------
// Cross QKV GEMM: 128x128 tiles, 512 threads.
// y=0: q from Xr (*0.25); y=1: K from Xl; y=2: V from Xl.
// At l=5 launched with grid.y=2 (V dead: no attn launch, corresp reads Q/K).
// ---------------------------------------------------------------------------
__global__ __launch_bounds__(512) void gemm_qkv_cross(
    const u16* __restrict__ Xl, const u16* __restrict__ Xr,
    const u16* __restrict__ cWi, const float* __restrict__ cbi,
    u16* __restrict__ QB, u16* __restrict__ KB, u16* __restrict__ VB) {
  __shared__ u16 As[128 * 136];
  __shared__ u16 Bs[128 * 136];
  const int tid = threadIdx.x;
  const int M0 = blockIdx.x * 128;
  const int y = blockIdx.y;
  const u16* X = (y == 0) ? Xr : Xl;
  const u16* Bw = cWi + (size_t)y * 128 * 128;
  const float* bias = cbi + y * 128;
  {
    const uint4* Bg = (const uint4*)Bw;
    const uint4* Ag = (const uint4*)(X + (size_t)M0 * 128);
    for (int t = tid; t < 2048; t += 512) {
      int row = t >> 4, cc = t & 15;
      *(uint4*)&As[row * 136 + cc * 8] = Ag[row * 16 + cc];
      *(uint4*)&Bs[row * 136 + cc * 8] = Bg[row * 16 + cc];
    }
  }
  __syncthreads();
  const int wave = tid >> 6, lane = tid & 63;
  const int wm = (wave >> 2) * 64, wn = (wave & 3) * 32;
  const int lr = lane & 15, kq = (lane >> 4) * 8;
  f32x4 acc[4][2] = {};
#pragma unroll
  for (int ks = 0; ks < 4; ++ks) {
    int ko = ks * 32 + kq;
    bf16x8 b0 = *(const bf16x8*)&Bs[(wn + lr) * 136 + ko];
    bf16x8 b1 = *(const bf16x8*)&Bs[(wn + 16 + lr) * 136 + ko];
#pragma unroll
    for (int tm = 0; tm < 4; ++tm) {
      bf16x8 a0 = *(const bf16x8*)&As[(wm + tm * 16 + lr) * 136 + ko];
      acc[tm][0] = __builtin_amdgcn_mfma_f32_16x16x32_bf16(a0, b0, acc[tm][0], 0, 0, 0);
      acc[tm][1] = __builtin_amdgcn_mfma_f32_16x16x32_bf16(a0, b1, acc[tm][1], 0, 0, 0);
    }
  }
  u16* outp = (y == 0) ? QB : ((y == 1) ? KB : VB);
  const float scale = (y == 0) ? 0.25f : 1.f;
  const int colq = lane & 15, rowq = (lane >> 4) * 4;
#pragma unroll
  for (int tm = 0; tm < 4; ++tm)
#pragma unroll
    for (int tn = 0; tn < 2; ++tn) {
#pragma unroll
      for (int r = 0; r < 4; ++r) {
        int row = M0 + wm + tm * 16 + rowq + r;
        int col = wn + tn * 16 + colq;
        float v = (acc[tm][tn][r] + bias[col]) * scale;
        int e = col >> 4, c = col & 15;
        int b = row & 127, pos = row >> 7;
        outp[((size_t)(b * NH + e) * W_ + pos) * HD + c] = f2bf(v);
      }
    }
}

// ---------------------------------------------------------------------------
// MFMA flash attention per (head e, batch-row b). Two-pass softmax. P stays
// in registers (sigma-permuted V); exp2 with log2e folded into Q-side staging.
// ---------------------------------------------------------------------------
__global__ __launch_bounds__(448) void attn_kernel(
    const u16* __restrict__ qb, const u16* __restrict__ kb,
    const u16* __restrict__ vb, const float* __restrict__ ALPHA,
    const float* __restrict__ BETA, const float* __restrict__ GAMMA,
    const float* __restrict__ DELTA, u16* __restrict__ obuf) {
  __shared__ u16 Ksh[224 * KSTR];
  __shared__ u16 Qsh[224 * KSTR];
  __shared__ u16 Vt[16 * VSTR];
  const int e = blockIdx.x, b = blockIdx.y;
  const size_t hb = (size_t)(b * NH + e);
  const int tid = threadIdx.x;
  const u32 ONE = 0x3F80u;
  const float LOG2E = 1.4426950408889634f;

  if (tid < 224) {
    const int j = tid;
    const uint4* src = (const uint4*)(kb + (hb * W_ + j) * HD);
    uint4 a = src[0], b2 = src[1];
    *(uint4*)&Ksh[j * KSTR] = a;
    *(uint4*)&Ksh[j * KSTR + 8] = b2;
    float G = GAMMA[hb * 224 + j];
    float D = DELTA[hb * 224 + j];
    float jf = (float)j;
    float P = (G * jf + D) * LOG2E;
    u16 Phi = f2bf(P);
    float Plo = P - __uint_as_float((u32)Phi << 16);
    u32* ex = (u32*)&Ksh[j * KSTR + 16];
    ex[0] = (u32)f2bf(G * LOG2E) | ((u32)Phi << 16);
    ex[1] = (u32)f2bf(Plo) | ((u32)f2bf(jf) << 16);
    ex[2] = ONE | (ONE << 16);
#pragma unroll
    for (int z = 3; z < 12; ++z) ex[z] = 0;
    const uint4* vsrc = (const uint4*)(vb + (hb * W_ + j) * HD);
    uint4 va = vsrc[0], vb4 = vsrc[1];
    u32 w[8] = {va.x, va.y, va.z, va.w, vb4.x, vb4.y, vb4.z, vb4.w};
    // sigma-permuted column so PV A-fragments come straight from registers
    const int jl = j & 31;
    const int qcol = (j & ~31) | (((jl >> 2) & 3) << 3) | ((jl >> 4) << 2) | (jl & 3);
#pragma unroll
    for (int c = 0; c < 16; ++c)
      Vt[c * VSTR + qcol] = (c & 1) ? (u16)(w[c >> 1] >> 16) : (u16)(w[c >> 1] & 0xFFFF);
  } else {
    const int i = tid - 224;
    const uint4* src = (const uint4*)(qb + (hb * W_ + i) * HD);
    uint4 a = src[0], b2 = src[1];
    u32 qa[8] = {a.x, a.y, a.z, a.w, b2.x, b2.y, b2.z, b2.w};
#pragma unroll
    for (int t = 0; t < 8; ++t)
      qa[t] = cvtpk(bflo(qa[t]) * LOG2E, bfhi(qa[t]) * LOG2E);
    *(uint4*)&Qsh[i * KSTR] = make_uint4(qa[0], qa[1], qa[2], qa[3]);
    *(uint4*)&Qsh[i * KSTR + 8] = make_uint4(qa[4], qa[5], qa[6], qa[7]);
    float al = ALPHA[hb * 224 + i];
    float be = BETA[hb * 224 + i];
    float ifl = (float)i;
    float Q = (be - al * ifl) * LOG2E;
    u16 Qhi = f2bf(Q);
    float Qlo = Q - __uint_as_float((u32)Qhi << 16);
    u32* ex = (u32*)&Qsh[i * KSTR + 16];
    ex[0] = (u32)f2bf(-ifl) | (ONE << 16);
    ex[1] = ONE | ((u32)f2bf(al * LOG2E) << 16);
    ex[2] = (u32)Qhi | ((u32)f2bf(Qlo) << 16);
#pragma unroll
    for (int z = 3; z < 12; ++z) ex[z] = 0;
  }
  __syncthreads();

  const int wid = tid >> 6, lane = tid & 63;
  const int g = lane >> 4, li = lane & 15;
  const int obase = (b & 128) ? ROWS_ : 0;
  const int blow = b & 127;

  for (int qt = wid * 2; qt < wid * 2 + 2; ++qt) {
    const int i0 = qt * 16;
    const bf16x8 Bq = *(const bf16x8*)&Qsh[(i0 + li) * KSTR + g * 8];
    f32x4 C[7][2];
#pragma unroll
    for (int js = 0; js < 7; ++js) {
      const bf16x8 A0 = *(const bf16x8*)&Ksh[(js * 32 + li) * KSTR + g * 8];
      const bf16x8 A1 = *(const bf16x8*)&Ksh[(js * 32 + 16 + li) * KSTR + g * 8];
      const f32x4 Z = {0.f, 0.f, 0.f, 0.f};
      C[js][0] = __builtin_amdgcn_mfma_f32_16x16x32_bf16(A0, Bq, Z, 0, 0, 0);
      C[js][1] = __builtin_amdgcn_mfma_f32_16x16x32_bf16(A1, Bq, Z, 0, 0, 0);
    }
    float m = -1e30f;
#pragma unroll
    for (int js = 0; js < 7; ++js)
#pragma unroll
      for (int h = 0; h < 2; ++h)
        m = fmaxf(m, fmaxf(fmaxf(C[js][h][0], C[js][h][1]), fmaxf(C[js][h][2], C[js][h][3])));
    m = fmaxf(m, __shfl_xor(m, 16));
    m = fmaxf(m, __shfl_xor(m, 32));
    f32x4 O = {0.f, 0.f, 0.f, 0.f};
    float lsum = 0.f;
#pragma unroll
    for (int js = 0; js < 7; ++js) {
      float p0 = EX2(C[js][0][0] - m), p1 = EX2(C[js][0][1] - m);
      float p2 = EX2(C[js][0][2] - m), p3 = EX2(C[js][0][3] - m);
      float p4 = EX2(C[js][1][0] - m), p5 = EX2(C[js][1][1] - m);
      float p6 = EX2(C[js][1][2] - m), p7 = EX2(C[js][1][3] - m);
      lsum += ((p0 + p1) + (p2 + p3)) + ((p4 + p5) + (p6 + p7));
      uint4 pu = make_uint4(cvtpk(p0, p1), cvtpk(p2, p3), cvtpk(p4, p5), cvtpk(p6, p7));
      const bf16x8 Ap = __builtin_bit_cast(bf16x8, pu);
      const bf16x8 Bv = *(const bf16x8*)&Vt[li * VSTR + js * 32 + g * 8];
      O = __builtin_amdgcn_mfma_f32_16x16x32_bf16(Ap, Bv, O, 0, 0, 0);
    }
    lsum += __shfl_xor(lsum, 16);
    lsum += __shfl_xor(lsum, 32);
#pragma unroll
    for (int r = 0; r < 4; ++r) {
      const float lr = __shfl(lsum, g * 4 + r);
      const int irow = i0 + g * 4 + r;
      obuf[((size_t)(obase + irow * 128 + blow)) * C_ + e * HD + li] = f2bf(O[r] * (1.f / lr));
    }
  }
}

// Gather x_l/x_r[b][c][h][w] -> bf16 rows p = img*28672 + w*128 + h*2 + b.
__global__ __launch_bounds__(256) void transpose_kernel(const float* __restrict__ x_l,
                                                        const float* __restrict__ x_r,
                                                        u16* __restrict__ xT) {
  __shared__ float tile[128][57];
  const int wt = blockIdx.x * 56, hi = blockIdx.y;
  const int img = blockIdx.z >> 1, bi = blockIdx.z & 1;
  const float* x = img ? x_r : x_l;
  const int wave = threadIdx.x >> 6, lane = threadIdx.x & 63;
  for (int c = wave; c < 128; c += 4) {
    if (lane < 56)
      tile[c][lane] = x[(((size_t)bi * 128 + c) * 64 + hi) * 224 + wt + lane];
  }
  __syncthreads();
  u32* dst = (u32*)xT;
  for (int w = wave; w < 56; w += 4) {
    int p = img * ROWS_ + (wt + w) * 128 + hi * 2 + bi;
    float a = tile[lane * 2][w], b2 = tile[lane * 2 + 1][w];
    dst[(size_t)p * 64 + lane] = (u32)f2bf(a) | ((u32)f2bf(b2) << 16);
  }
}

// ---------------------------------------------------------------------------
// Final soft-argmax, MFMA version.
// ---------------------------------------------------------------------------
__global__ __launch_bounds__(448) void corresp_kernel(
    const u16* __restrict__ qb, const u16* __restrict__ kb,
    const float* __restrict__ ALPHA, const float* __restrict__ BETA,
    const float* __restrict__ GAMMA, const float* __restrict__ DELTA,
    float* __restrict__ out) {
  __shared__ u16 Ksh[224 * 136];   // 60,928 B
  __shared__ float Gs[224], Ds[224];
  const int b = blockIdx.x, tid = threadIdx.x;
  if (tid < 224) {
    const int j = tid;
#pragma unroll
    for (int e = 0; e < 8; ++e) {
      const uint4* src = (const uint4*)(kb + ((size_t)(b * 8 + e) * 224 + j) * 16);
      *(uint4*)&Ksh[j * 136 + e * 16] = src[0];
      *(uint4*)&Ksh[j * 136 + e * 16 + 8] = src[1];
    }
    float gs = 0.f, ds = 0.f;
#pragma unroll
    for (int e = 0; e < 8; ++e) {
      gs += GAMMA[((size_t)(b * 8 + e)) * 224 + j];
      ds += DELTA[((size_t)(b * 8 + e)) * 224 + j];
    }
    Gs[j] = gs;
    Ds[j] = ds;
  }
  __syncthreads();
  const int wid = tid >> 6, lane = tid & 63;
  const int g = lane >> 4, li = lane & 15;
  const int i = blockIdx.y * 112 + wid * 16 + li;
  bf16x8 Bq[4];
#pragma unroll
  for (int ks = 0; ks < 4; ++ks) {
    const int e2 = ks * 2 + (g >> 1), c0 = (g & 1) * 8;
    Bq[ks] = *(const bf16x8*)&qb[((size_t)(b * 8 + e2) * 224 + i) * 16 + c0];
  }
  f32x4 C[14];
#pragma unroll
  for (int js = 0; js < 14; ++js) {
    f32x4 acc = {0.f, 0.f, 0.f, 0.f};
#pragma unroll
    for (int ks = 0; ks < 4; ++ks) {
      const bf16x8 A = *(const bf16x8*)&Ksh[(js * 16 + li) * 136 + ks * 32 + g * 8];
      acc = __builtin_amdgcn_mfma_f32_16x16x32_bf16(A, Bq[ks], acc, 0, 0, 0);
    }
    C[js] = acc;
  }
  float ai = 0.f, bi_ = 0.f;
#pragma unroll
  for (int e = 0; e < 8; ++e) {
    ai += ALPHA[((size_t)(b * 8 + e)) * 224 + i];
    bi_ += BETA[((size_t)(b * 8 + e)) * 224 + i];
  }
  const float ifl = (float)i;
  float m = -1e30f;
#pragma unroll
  for (int js = 0; js < 14; ++js) {
#pragma unroll
    for (int r = 0; r < 4; ++r) {
      const int j = js * 16 + g * 4 + r;
      float s = C[js][r] + ((float)j - ifl) * (ai + Gs[j]) + bi_ + Ds[j];
      C[js][r] = s;
      m = fmaxf(m, s);
    }
  }
  m = fmaxf(m, __shfl_xor(m, 16));
  m = fmaxf(m, __shfl_xor(m, 32));
  float l = 0.f, wj = 0.f;
#pragma unroll
  for (int js = 0; js < 14; ++js) {
#pragma unroll
    for (int r = 0; r < 4; ++r) {
      const float p = __expf(C[js][r] - m);
      l += p;
      wj += p * (float)(js * 16 + g * 4 + r);
    }
  }
  l += __shfl_xor(l, 16);
  l += __shfl_xor(l, 32);
  wj += __shfl_xor(wj, 16);
  wj += __shfl_xor(wj, 32);
  if (g == 0) out[(size_t)b * 224 + i] = ifl - wj / fmaxf(l, 1e-30f);
}

// Single-launch conversion of all five weight tensors to one bf16 buffer.
#define OFF_FEAT 0
#define OFF_SWI 16384
#define OFF_SWO 311296
#define OFF_CWI 409600
#define OFF_CWO 704512
#define N_WALL 802816
__global__ __launch_bounds__(256) void cvt_all_kernel(
    const float* __restrict__ feat_w, const float* __restrict__ self_Wi,
    const float* __restrict__ self_Wo, const float* __restrict__ cross_Wi,
    const float* __restrict__ cross_Wo, u16* __restrict__ dst) {
  int idx = blockIdx.x * 256 + threadIdx.x;
  if (idx >= N_WALL) return;
  float v;
  if (idx < OFF_SWI)       v = feat_w[idx];
  else if (idx < OFF_SWO)  v = self_Wi[idx - OFF_SWI];
  else if (idx < OFF_CWI)  v = self_Wo[idx - OFF_SWO];
  else if (idx < OFF_CWO)  v = cross_Wi[idx - OFF_CWI];
  else                     v = cross_Wo[idx - OFF_CWO];
  dst[idx] = f2bf(v);
}

extern "C" void kernel_launch(void* const* d_in, const int* in_sizes, int n_in,
                              void* d_out, int out_size, void* d_ws, size_t ws_size,
                              hipStream_t stream) {
  (void)in_sizes; (void)n_in; (void)out_size; (void)ws_size;
  const float* x_l = (const float*)d_in[0];
  const float* x_r = (const float*)d_in[1];
  const float* feat_w = (const float*)d_in[2];
  const float* feat_b = (const float*)d_in[3];
  const float* self_Wi = (const float*)d_in[4];
  const float* self_bi = (const float*)d_in[5];
  const float* self_Wo = (const float*)d_in[6];
  const float* self_bo = (const float*)d_in[7];
  const float* cross_Wi = (const float*)d_in[8];
  const float* cross_bi = (const float*)d_in[9];
  const float* cross_Wo = (const float*)d_in[10];
  const float* cross_bo = (const float*)d_in[11];
  const float* ln_g = (const float*)d_in[12];
  const float* ln_b = (const float*)d_in[13];

  char* ws = (char*)d_ws;
  size_t off = 0;
  auto alloc = [&](size_t bytes) {
    char* p = ws + off;
    off += (bytes + 255) & ~(size_t)255;
    return p;
  };
  // Total ~97 MB — under the R6-proven ~112 MB budget. XB aliases OB:
  // XB live range is tab->qkv, OB live range is attn->out-proj (disjoint).
  float* XA = (float*)alloc((size_t)2 * ROWS_ * C_ * 4);   // residual (in-place LN)
  u16* QB = (u16*)alloc((size_t)256 * NH * W_ * HD * 2);   // also XT scratch
  u16* KB = (u16*)alloc((size_t)256 * NH * W_ * HD * 2);
  u16* VB = (u16*)alloc((size_t)256 * NH * W_ * HD * 2);
  u16* OB = (u16*)alloc((size_t)2 * ROWS_ * C_ * 2);
  u16* WALL = (u16*)alloc((size_t)N_WALL * 2);
  float* PREP = (float*)alloc((size_t)12 * PREP_STRIDE * 4);
  float* ALPHA = (float*)alloc((size_t)256 * NH * W_ * 4);
  float* BETA = (float*)alloc((size_t)256 * NH * W_ * 4);
  float* GAMMA = (float*)alloc((size_t)256 * NH * W_ * 4);
  float* DELTA = (float*)alloc((size_t)256 * NH * W_ * 4);
  u16* XB = OB;   // alias — disjoint live ranges

  cvt_all_kernel<<<3136, 256, 0, stream>>>(feat_w, self_Wi, self_Wo, cross_Wi, cross_Wo, WALL);
  prep_kernel<<<dim3(12, 8), 256, 0, stream>>>(self_Wi, self_bi, cross_Wi, cross_bi, PREP);

  transpose_kernel<<<dim3(4, 64, 4), 256, 0, stream>>>(x_l, x_r, QB);
  gemm_plain<<<dim3(896, 2), 256, 0, stream>>>(QB, WALL + OFF_FEAT, feat_b, 5, XA);

  for (int l = 0; l < 6; ++l) {
    const u16* sWi = WALL + OFF_SWI + (size_t)l * 384 * 128;
    const u16* sWo = WALL + OFF_SWO + (size_t)l * 128 * 128;
    const u16* cWi = WALL + OFF_CWI + (size_t)l * 384 * 128;
    const u16* cWo = WALL + OFF_CWO + (size_t)l * 128 * 128;
    const float* sbi = self_bi + l * 384;
    const float* sbo = self_bo + l * 128;
    const float* cbi = cross_bi + l * 384;
    const float* cbo = cross_bo + l * 128;
    const float* ps = PREP + (size_t)(l * 2) * PREP_STRIDE;
    const float* pc = PREP + (size_t)(l * 2 + 1) * PREP_STRIDE;

    // --- self attention on xl AND xr: X = LN(X) (+tables+XB), qkv, attn, +=proj ---
    tab_kernel<<<1792, 256, 0, stream>>>(XA, ln_g, ln_b, ps, ps + 4096, ALPHA, BETA,
                                         ps + 2048, ps + 4112, GAMMA, DELTA, XB, 0);
    gemm_qkv_self<<<dim3(448, 3), 512, 0, stream>>>(XB, sWi, sbi, QB, KB, VB);
    attn_kernel<<<dim3(8, 256), 448, 0, stream>>>(QB, KB, VB, ALPHA, BETA, GAMMA, DELTA, OB);
    gemm_plain<<<dim3(896, 2), 256, 0, stream>>>(OB, sWo, sbo, 4, XA);

    // --- cross attention: q from xr, k/v from xl; X = LN(X) first ---
    tab_kernel<<<1792, 256, 0, stream>>>(XA, ln_g, ln_b, pc, pc + 4096, ALPHA, BETA,
                                         pc + 2048, pc + 4112, GAMMA, DELTA, XB, 1);
    // l==5: V (y=2) is dead — no attn launch follows and corresp reads QB/KB only.
    gemm_qkv_cross<<<dim3(224, (l < 5) ? 3 : 2), 512, 0, stream>>>(
        XB, XB + (size_t)ROWS_ * C_, cWi, cbi, QB, KB, VB);
    if (l < 5) {
      attn_kernel<<<dim3(8, 128), 448, 0, stream>>>(QB, KB, VB, ALPHA, BETA, GAMMA, DELTA, OB);
      gemm_plain<<<dim3(448, 2), 256, 0, stream>>>(OB, cWo, cbo, 4, XA);  // xl half only
    }
    // l == 5: attention output / x updates dead; corresp reads QB/KB + tables.
  }
  corresp_kernel<<<dim3(128, 2), 448, 0, stream>>>(QB, KB, ALPHA, BETA, GAMMA, DELTA,
                                                   (float*)d_out);
}